// Round 10
// baseline (296.807 us; speedup 1.0000x reference)
//
#include <hip/hip_runtime.h>
#include <hip/hip_bf16.h>

// ---------------------------------------------------------------------------
// RGCN link predictor. Atomic-free CSR build + CSR-pull + bf16 MFMA GEMMs.
//   rgcn_conv(x) = x@root + b + sum_r segsum_dst( H_r[src] ) / max(cnt_r[dst],1)
//   Pulls: channel-exclusive lane groups + 4-way edge-split per node
//   (shfl_xor combine) + chunk-4 batched gather issue. erec packed to 4B
//   (row | cnt<<19); scale via v_rcp. Plain cached loads/stores (nt hints
//   measured regression R7). Decoder on MFMA.
//   CSR build: 2-level bucket sort by dst (256-dst windows), 512 edge tiles
//   (R9: 256 tiles left part_scatter latency-bound at 1 block/CU, 41us).
//   scan_top folded into consumers via local LDS scan of rowsum. Layer-1
//   GEMM blocks ride along inside the CSR-chain dispatches. 8 dispatches.
// ---------------------------------------------------------------------------

typedef short bf16x8 __attribute__((ext_vector_type(8)));
typedef float f32x4 __attribute__((ext_vector_type(4)));
typedef float f32x2 __attribute__((ext_vector_type(2)));
typedef unsigned u32x4 __attribute__((ext_vector_type(4)));

__device__ __forceinline__ unsigned short f2bf(float f) {
  union { float f; unsigned u; } x; x.f = f;
  unsigned r = x.u + 0x7FFF + ((x.u >> 16) & 1);  // RNE
  return (unsigned short)(r >> 16);
}
__device__ __forceinline__ float bf2f(unsigned short h) {
  union { unsigned u; float f; } x; x.u = ((unsigned)h) << 16;
  return x.f;
}
__device__ __forceinline__ f32x2 bfpair(unsigned u) {
  union { unsigned u; float f; } a, b;
  a.u = u << 16; b.u = u & 0xFFFF0000u;
  f32x2 r; r[0] = a.f; r[1] = b.f; return r;
}
__device__ __forceinline__ unsigned pk2(float a, float b) {
  return (unsigned)f2bf(a) | ((unsigned)f2bf(b) << 16);
}

// pack weights into MFMA B-fragment order, split hi/lo.
template <int K, int TN>
__device__ __forceinline__ void pack_one(
    int e, const float* __restrict__ W, const float* __restrict__ root,
    ushort* __restrict__ Bh, ushort* __restrict__ Bl) {
  int slab = e / (K * TN), r = e % (K * TN);
  int k = r / TN, n = r % TN;
  float v = (slab < 3) ? W[(size_t)slab * K * TN + k * TN + n] : root[(size_t)k * TN + n];
  int kc = k >> 5, quad = (k >> 3) & 3, j = k & 7, nt = n >> 4, nn = n & 15;
  int NTt = TN / 16;
  int didx = slab * K * TN + ((kc * NTt + nt) * 64 + quad * 16 + nn) * 8 + j;
  unsigned short h = f2bf(v);
  Bh[didx] = h;
  Bl[didx] = f2bf(v - bf2f(h));
}

// blocks 0..511: histogram of dst>>8 per 512-edge-tile. blocks 512..687:
// weight packing (layer1, layer2, decoder Wd1 -> bf16 B-frag order).
__global__ __launch_bounds__(256) void hist_pack_kernel(
    const int* __restrict__ ei, int* __restrict__ hist, int E, int tile, int NBUCK,
    const float* __restrict__ W1, const float* __restrict__ root1,
    ushort* __restrict__ Bh1, ushort* __restrict__ Bl1,
    const float* __restrict__ W2, const float* __restrict__ root2,
    ushort* __restrict__ Bh2, ushort* __restrict__ Bl2,
    const float* __restrict__ Wd1, ushort* __restrict__ Bd1h) {
  int tid = threadIdx.x;
  if (blockIdx.x >= 512) {
    int e = (blockIdx.x - 512) * 256 + tid;
    if (e < 32768) {
      pack_one<128, 64>(e, W1, root1, Bh1, Bl1);
    } else if (e < 32768 + 8192) {
      pack_one<64, 32>(e - 32768, W2, root2, Bh2, Bl2);
    } else if (e < 32768 + 8192 + 4096) {
      int r = e - 32768 - 8192;          // Wd1: K=64, TN=64, single slab
      int k = r >> 6, n = r & 63;
      int kc = k >> 5, quad = (k >> 3) & 3, j = k & 7, nt = n >> 4, nn = n & 15;
      Bd1h[((kc * 4 + nt) * 64 + quad * 16 + nn) * 8 + j] = f2bf(Wd1[k * 64 + n]);
    }
    return;
  }
  __shared__ int lh[512];
  for (int i = tid; i < 512; i += 256) lh[i] = 0;
  __syncthreads();
  int e0 = blockIdx.x * tile, e1 = min(E, e0 + tile);
  for (int e = e0 + tid; e < e1; e += 256) atomicAdd(&lh[ei[E + e] >> 8], 1);
  __syncthreads();
  for (int i = tid; i < NBUCK; i += 256) hist[i * 512 + blockIdx.x] = lh[i];
}

// ---------------------------------------------------------------------------
// Layer-1 split-bf16 MFMA GEMM as a device body so its blocks can ride along
// inside the CSR-chain dispatches. Block = 4 waves x 16 rows = 64 rows.
// H slabs (0-2): Ah*Bh + Al*Bh, bf16 out. z slab (3): + Ah*Bl, fp32 + bias.
// ---------------------------------------------------------------------------
__device__ __forceinline__ void gemm1_body(
    int bid, int4* __restrict__ bsm,
    const float* __restrict__ A, const ushort* __restrict__ Bh,
    const ushort* __restrict__ Bl, const float* __restrict__ bias,
    ushort* __restrict__ Hb, float* __restrict__ z, int n) {
  constexpr int K = 128, TN = 64;
  constexpr int KC = K / 32;       // 4
  constexpr int NTt = TN / 16;     // 4
  constexpr int HALF = K * TN / 8; // 1024 int4 = 16 KB per half
  const int tid = threadIdx.x;
  const int w = tid >> 6, lane = tid & 63;
  const int quad = lane >> 4, nn = lane & 15;
  const int rowBase = bid * 64 + w * 16;

  int row = rowBase + nn;
  if (row >= n) row = n - 1;  // clamp; stores are guarded
  const float* ap = &A[(size_t)row * K + quad * 8];
  bf16x8 ah[KC], al[KC];
#pragma unroll
  for (int kc = 0; kc < KC; kc++) {
    float4 f0 = *(const float4*)(ap + kc * 32);
    float4 f1 = *(const float4*)(ap + kc * 32 + 4);
    float f[8] = {f0.x, f0.y, f0.z, f0.w, f1.x, f1.y, f1.z, f1.w};
#pragma unroll
    for (int j = 0; j < 8; j++) {
      unsigned short h = f2bf(f[j]);
      ah[kc][j] = (short)h;
      al[kc][j] = (short)f2bf(f[j] - bf2f(h));
    }
  }

  const short* bsp = (const short*)bsm;

#pragma unroll 1
  for (int slab = 0; slab < 4; slab++) {
    __syncthreads();
    {
      const int4* gh = (const int4*)(Bh + (size_t)slab * K * TN);
      for (int i = tid; i < HALF; i += 256) bsm[i] = gh[i];
      if (slab == 3) {
        const int4* gl = (const int4*)(Bl + (size_t)slab * K * TN);
        for (int i = tid; i < HALF; i += 256) bsm[HALF + i] = gl[i];
      }
    }
    __syncthreads();

    f32x4 acc[NTt];
#pragma unroll
    for (int j = 0; j < NTt; j++) acc[j] = (f32x4){0.f, 0.f, 0.f, 0.f};

#pragma unroll
    for (int kc = 0; kc < KC; kc++) {
#pragma unroll
      for (int nt = 0; nt < NTt; nt++) {
        bf16x8 b = *(const bf16x8*)&bsp[((kc * NTt + nt) * 64 + lane) * 8];
        acc[nt] = __builtin_amdgcn_mfma_f32_16x16x32_bf16(ah[kc], b, acc[nt], 0, 0, 0);
        acc[nt] = __builtin_amdgcn_mfma_f32_16x16x32_bf16(al[kc], b, acc[nt], 0, 0, 0);
      }
    }
    if (slab == 3) {
#pragma unroll
      for (int kc = 0; kc < KC; kc++) {
#pragma unroll
        for (int nt = 0; nt < NTt; nt++) {
          bf16x8 b = *(const bf16x8*)&bsp[(HALF * 8) + ((kc * NTt + nt) * 64 + lane) * 8];
          acc[nt] = __builtin_amdgcn_mfma_f32_16x16x32_bf16(ah[kc], b, acc[nt], 0, 0, 0);
        }
      }
    }

    int grow0 = rowBase + quad * 4;
#pragma unroll
    for (int nt = 0; nt < NTt; nt++) {
      int col = nt * 16 + nn;
#pragma unroll
      for (int rg = 0; rg < 4; rg++) {
        int grow = grow0 + rg;
        if (grow < n) {
          float v = acc[nt][rg];
          if (slab == 3) z[(size_t)grow * TN + col] = v + bias[col];
          else Hb[((size_t)slab * n + grow) * TN + col] = f2bf(v);
        }
      }
    }
  }
}

// --- fused chain kernels: blockIdx < nChain -> chain work, else gemm1 slice.
// All share a 32 KB LDS buffer (gemm needs 2*HALF int4; chain aliases ints).

// parallel scan of each bucket row (512 entries, 2/thread) -> exclusive,
// + rowsum
__global__ __launch_bounds__(256, 4) void scan_rows_gemm_kernel(
    int* __restrict__ hist, int* __restrict__ rowsum, int nChain, int gemmBase,
    const float* __restrict__ A, const ushort* __restrict__ Bh,
    const ushort* __restrict__ Bl, const float* __restrict__ bias,
    ushort* __restrict__ Hb, float* __restrict__ z, int n) {
  __shared__ int4 smem[2048];
  if ((int)blockIdx.x >= nChain) {
    gemm1_body(gemmBase + (int)blockIdx.x - nChain, smem, A, Bh, Bl, bias, Hb, z, n);
    return;
  }
  int* sA = (int*)smem;
  int* sB = sA + 256;
  int t = threadIdx.x;
  int* row = hist + blockIdx.x * 512;
  int v0 = row[2 * t], v1 = row[2 * t + 1];
  int v = v0 + v1;
  sA[t] = v;
  __syncthreads();
  int* src = sA; int* dst = sB;
  for (int off = 1; off < 256; off <<= 1) {
    int x = src[t];
    if (t >= off) x += src[t - off];
    dst[t] = x;
    __syncthreads();
    int* tmp = src; src = dst; dst = tmp;
  }
  int excl = src[t] - v;
  row[2 * t] = excl;
  row[2 * t + 1] = excl + v0;
  if (t == 255) rowsum[blockIdx.x] = src[255];
}

// scatter edges into coarse buckets (512 tiles -> 2 chain blocks/CU).
// rowbase derived by a local LDS scan of rowsum (NBUCK<=511 ints).
__global__ __launch_bounds__(256, 4) void part_scatter_gemm_kernel(
    const int* __restrict__ ei, const int* __restrict__ et,
    const int* __restrict__ hist, const int* __restrict__ rowsum,
    unsigned* __restrict__ rec, int E, int tile, int NBUCK,
    int nChain, int gemmBase,
    const float* __restrict__ A, const ushort* __restrict__ Bh,
    const ushort* __restrict__ Bl, const float* __restrict__ bias,
    ushort* __restrict__ Hb, float* __restrict__ z, int n) {
  __shared__ int4 smem[2048];
  if ((int)blockIdx.x >= nChain) {
    gemm1_body(gemmBase + (int)blockIdx.x - nChain, smem, A, Bh, Bl, bias, Hb, z, n);
    return;
  }
  int* sA = (int*)smem;      // 256
  int* sB = sA + 256;        // 256
  int* rb = sB + 256;        // 512 rowbase
  int* ctr = rb + 512;       // 512
  int t = threadIdx.x;
  // local exclusive scan of rowsum (2 elems/thread, NBUCK <= 511)
  int e0 = 2 * t, e1 = 2 * t + 1;
  int v0 = (e0 < NBUCK) ? rowsum[e0] : 0;
  int v1 = (e1 < NBUCK) ? rowsum[e1] : 0;
  int v = v0 + v1;
  sA[t] = v;
  __syncthreads();
  int* src = sA; int* dst = sB;
  for (int off = 1; off < 256; off <<= 1) {
    int x = src[t];
    if (t >= off) x += src[t - off];
    dst[t] = x;
    __syncthreads();
    int* tmp = src; src = dst; dst = tmp;
  }
  int excl = src[t] - v;
  rb[e0] = excl;
  rb[e1] = excl + v0;
  __syncthreads();
  for (int i = t; i < NBUCK; i += 256)
    ctr[i] = hist[i * 512 + blockIdx.x] + rb[i];
  __syncthreads();
  int e0g = blockIdx.x * tile, e1g = min(E, e0g + tile);
  for (int e = e0g + t; e < e1g; e += 256) {
    int s = ei[e];
    int d = ei[E + e];
    int rt = et[e];
    int p = atomicAdd(&ctr[d >> 8], 1);
    rec[p] = (unsigned)(s | (rt << 20) | ((d & 255) << 22));
  }
}

// one block per 256-dst window: per-(rel,dst) counts, sd, and final dst-grouped
// erec = (row | cnt<<19) 4B packed. rowbase via local rowsum scan.
__global__ __launch_bounds__(256, 4) void bucket_build_gemm_kernel(
    const unsigned* __restrict__ rec, const int* __restrict__ rowsum,
    int2* __restrict__ sd, unsigned* __restrict__ erec, int N, int NBUCK,
    int nChain, int gemmBase,
    const float* __restrict__ A, const ushort* __restrict__ Bh,
    const ushort* __restrict__ Bl, const float* __restrict__ bias,
    ushort* __restrict__ Hb, float* __restrict__ z) {
  __shared__ int4 smem[2048];
  if ((int)blockIdx.x >= nChain) {
    gemm1_body(gemmBase + (int)blockIdx.x - nChain, smem, A, Bh, Bl, bias, Hb, z, N);
    return;
  }
  int* c3 = (int*)smem;       // 768
  int* sA = c3 + 768;         // 256
  int* sB = sA + 256;         // 256
  int* cur = sB + 256;        // 256
  int* rb = cur + 256;        // 512 rowbase
  int tid = threadIdx.x;
  // local exclusive scan of rowsum -> rb (rb[NBUCK] = E automatically)
  {
    int e0 = 2 * tid, e1 = 2 * tid + 1;
    int v0 = (e0 < NBUCK) ? rowsum[e0] : 0;
    int v1 = (e1 < NBUCK) ? rowsum[e1] : 0;
    int v = v0 + v1;
    sA[tid] = v;
    __syncthreads();
    int* src = sA; int* dst = sB;
    for (int off = 1; off < 256; off <<= 1) {
      int x = src[tid];
      if (tid >= off) x += src[tid - off];
      dst[tid] = x;
      __syncthreads();
      int* tmp = src; src = dst; dst = tmp;
    }
    int excl = src[tid] - v;
    rb[e0] = excl;
    rb[e1] = excl + v0;
    __syncthreads();
  }
  int dstBase = blockIdx.x << 8;
  int bs = rb[blockIdx.x], be = rb[blockIdx.x + 1];
  for (int i = tid; i < 768; i += 256) c3[i] = 0;
  __syncthreads();
  for (int i = bs + tid; i < be; i += 256) {
    unsigned r = rec[i];
    atomicAdd(&c3[((r >> 20) & 3) * 256 + (r >> 22)], 1);
  }
  __syncthreads();
  int dgv = c3[tid] + c3[256 + tid] + c3[512 + tid];
  sA[tid] = dgv;
  __syncthreads();
  int* src = sA; int* dst = sB;
  for (int off = 1; off < 256; off <<= 1) {
    int x = src[tid];
    if (tid >= off) x += src[tid - off];
    dst[tid] = x;
    __syncthreads();
    int* tmp = src; src = dst; dst = tmp;
  }
  int excl = src[tid] - dgv;
  cur[tid] = bs + excl;
  if (dstBase + tid < N) sd[dstBase + tid] = make_int2(bs + excl, dgv);
  __syncthreads();
  for (int i = bs + tid; i < be; i += 256) {
    unsigned r = rec[i];
    int dloc = r >> 22;
    int rt = (r >> 20) & 3;
    int p = atomicAdd(&cur[dloc], 1);
    unsigned cnt = (unsigned)c3[rt * 256 + dloc];  // >=1, < 2^13
    erec[p] = (unsigned)(rt * N + (int)(r & 0xFFFFF)) | (cnt << 19);
  }
}

// Layer-2 pure-bf16 MFMA GEMM (A = z1b bf16, no split). K=64, TN=32.
__global__ __launch_bounds__(256, 4) void mfma_gemm2_kernel(
    const ushort* __restrict__ Ab, const ushort* __restrict__ Bh,
    const ushort* __restrict__ Bl, const float* __restrict__ bias,
    ushort* __restrict__ Hb, float* __restrict__ z2r, int n) {
  constexpr int KC = 2, NTt = 2, HALF = 64 * 32 / 8;
  __shared__ int4 bsm[2 * HALF];
  const int tid = threadIdx.x;
  const int w = tid >> 6, lane = tid & 63;
  const int quad = lane >> 4, nn = lane & 15;
  const int rowBase = blockIdx.x * 64 + w * 16;

  int row = rowBase + nn;
  if (row >= n) row = n - 1;
  const ushort* ap = &Ab[(size_t)row * 64 + quad * 8];
  bf16x8 ah[KC];
  ah[0] = *(const bf16x8*)(ap);
  ah[1] = *(const bf16x8*)(ap + 32);

  const short* bsp = (const short*)bsm;

#pragma unroll 1
  for (int slab = 0; slab < 4; slab++) {
    __syncthreads();
    {
      const int4* gh = (const int4*)(Bh + (size_t)slab * 64 * 32);
      for (int i = tid; i < HALF; i += 256) bsm[i] = gh[i];
      if (slab == 3) {
        const int4* gl = (const int4*)(Bl + (size_t)slab * 64 * 32);
        for (int i = tid; i < HALF; i += 256) bsm[HALF + i] = gl[i];
      }
    }
    __syncthreads();

    f32x4 acc[NTt];
#pragma unroll
    for (int j = 0; j < NTt; j++) acc[j] = (f32x4){0.f, 0.f, 0.f, 0.f};

#pragma unroll
    for (int kc = 0; kc < KC; kc++) {
#pragma unroll
      for (int nt = 0; nt < NTt; nt++) {
        bf16x8 b = *(const bf16x8*)&bsp[((kc * NTt + nt) * 64 + lane) * 8];
        acc[nt] = __builtin_amdgcn_mfma_f32_16x16x32_bf16(ah[kc], b, acc[nt], 0, 0, 0);
      }
    }
    if (slab == 3) {
#pragma unroll
      for (int kc = 0; kc < KC; kc++) {
#pragma unroll
        for (int nt = 0; nt < NTt; nt++) {
          bf16x8 b = *(const bf16x8*)&bsp[(HALF * 8) + ((kc * NTt + nt) * 64 + lane) * 8];
          acc[nt] = __builtin_amdgcn_mfma_f32_16x16x32_bf16(ah[kc], b, acc[nt], 0, 0, 0);
        }
      }
    }

    int grow0 = rowBase + quad * 4;
#pragma unroll
    for (int nt = 0; nt < NTt; nt++) {
      int col = nt * 16 + nn;
#pragma unroll
      for (int rg = 0; rg < 4; rg++) {
        int grow = grow0 + rg;
        if (grow < n) {
          float v = acc[nt][rg];
          if (slab == 3) z2r[(size_t)grow * 32 + col] = v + bias[col];
          else Hb[((size_t)slab * n + grow) * 32 + col] = f2bf(v);
        }
      }
    }
  }
}

// ---- pull, C=64: 32 lanes/node = 8 channel-lanes x 4 edge-quarters.
// Chunk-4 batched issue; 4B erec (row|cnt<<19), v_rcp scale; cached loads.
__global__ __launch_bounds__(256) void pull64_kernel(
    const ushort* __restrict__ Hb, const unsigned* __restrict__ erec,
    const int2* __restrict__ sd, const float* __restrict__ z1r,
    ushort* __restrict__ z1b, int N) {
  int t = blockIdx.x * 256 + threadIdx.x;
  int w = t >> 5;  // node
  if (w >= N) return;
  int q = threadIdx.x & 7;         // channel group (8 ch = 16B)
  int k = (threadIdx.x >> 3) & 3;  // edge quarter
  int2 s2 = sd[w];
  int j0 = s2.x + ((s2.y * k) >> 2);
  int j1 = s2.x + ((s2.y * (k + 1)) >> 2);
  f32x2 a0 = {0.f, 0.f}, a1 = a0, a2 = a0, a3 = a0;
  int j = j0;
  for (; j + 4 <= j1; j += 4) {
    unsigned r0 = erec[j], r1 = erec[j + 1], r2 = erec[j + 2], r3 = erec[j + 3];
    u32x4 v0 = *(const u32x4*)&Hb[(size_t)(r0 & 0x7FFFF) * 64 + q * 8];
    u32x4 v1 = *(const u32x4*)&Hb[(size_t)(r1 & 0x7FFFF) * 64 + q * 8];
    u32x4 v2 = *(const u32x4*)&Hb[(size_t)(r2 & 0x7FFFF) * 64 + q * 8];
    u32x4 v3 = *(const u32x4*)&Hb[(size_t)(r3 & 0x7FFFF) * 64 + q * 8];
    float f0 = __builtin_amdgcn_rcpf((float)(r0 >> 19));
    float f1 = __builtin_amdgcn_rcpf((float)(r1 >> 19));
    float f2 = __builtin_amdgcn_rcpf((float)(r2 >> 19));
    float f3 = __builtin_amdgcn_rcpf((float)(r3 >> 19));
    f32x2 s0 = {f0, f0}, s1 = {f1, f1}, s2v = {f2, f2}, s3 = {f3, f3};
    a0 += bfpair(v0[0]) * s0; a1 += bfpair(v0[1]) * s0;
    a2 += bfpair(v0[2]) * s0; a3 += bfpair(v0[3]) * s0;
    a0 += bfpair(v1[0]) * s1; a1 += bfpair(v1[1]) * s1;
    a2 += bfpair(v1[2]) * s1; a3 += bfpair(v1[3]) * s1;
    a0 += bfpair(v2[0]) * s2v; a1 += bfpair(v2[1]) * s2v;
    a2 += bfpair(v2[2]) * s2v; a3 += bfpair(v2[3]) * s2v;
    a0 += bfpair(v3[0]) * s3; a1 += bfpair(v3[1]) * s3;
    a2 += bfpair(v3[2]) * s3; a3 += bfpair(v3[3]) * s3;
  }
  for (; j < j1; j++) {
    unsigned r = erec[j];
    float sc = __builtin_amdgcn_rcpf((float)(r >> 19));
    f32x2 sc2 = {sc, sc};
    u32x4 v = *(const u32x4*)&Hb[(size_t)(r & 0x7FFFF) * 64 + q * 8];
    a0 += bfpair(v[0]) * sc2;
    a1 += bfpair(v[1]) * sc2;
    a2 += bfpair(v[2]) * sc2;
    a3 += bfpair(v[3]) * sc2;
  }
  // combine the 4 quarters (lanes differing in tid bits 3-4)
#pragma unroll
  for (int m = 8; m <= 16; m <<= 1) {
    a0[0] += __shfl_xor(a0[0], m); a0[1] += __shfl_xor(a0[1], m);
    a1[0] += __shfl_xor(a1[0], m); a1[1] += __shfl_xor(a1[1], m);
    a2[0] += __shfl_xor(a2[0], m); a2[1] += __shfl_xor(a2[1], m);
    a3[0] += __shfl_xor(a3[0], m); a3[1] += __shfl_xor(a3[1], m);
  }
  if (k == 0) {
    const float4* zr = (const float4*)&z1r[(size_t)w * 64 + q * 8];
    float4 r0 = zr[0], r1 = zr[1];
    uint4 st;
    st.x = pk2(fmaxf(r0.x + a0[0], 0.f), fmaxf(r0.y + a0[1], 0.f));
    st.y = pk2(fmaxf(r0.z + a1[0], 0.f), fmaxf(r0.w + a1[1], 0.f));
    st.z = pk2(fmaxf(r1.x + a2[0], 0.f), fmaxf(r1.y + a2[1], 0.f));
    st.w = pk2(fmaxf(r1.z + a3[0], 0.f), fmaxf(r1.w + a3[1], 0.f));
    *(uint4*)&z1b[(size_t)w * 64 + q * 8] = st;
  }
}

// ---- pull, C=32: 16 lanes/node = 4 channel-lanes x 4 edge-quarters.
// Chunk-4 batched issue; 4B erec; shfl_xor (4,8). No ReLU.
__global__ __launch_bounds__(256) void pull32_kernel(
    const ushort* __restrict__ Hb, const unsigned* __restrict__ erec,
    const int2* __restrict__ sd, const float* __restrict__ z2r,
    ushort* __restrict__ z2b, int N) {
  int t = blockIdx.x * 256 + threadIdx.x;
  int w = t >> 4;  // node
  if (w >= N) return;
  int q = threadIdx.x & 3;         // channel group
  int k = (threadIdx.x >> 2) & 3;  // edge quarter
  int2 s2 = sd[w];
  int j0 = s2.x + ((s2.y * k) >> 2);
  int j1 = s2.x + ((s2.y * (k + 1)) >> 2);
  f32x2 a0 = {0.f, 0.f}, a1 = a0, a2 = a0, a3 = a0;
  int j = j0;
  for (; j + 4 <= j1; j += 4) {
    unsigned r0 = erec[j], r1 = erec[j + 1], r2 = erec[j + 2], r3 = erec[j + 3];
    u32x4 v0 = *(const u32x4*)&Hb[(size_t)(r0 & 0x7FFFF) * 32 + q * 8];
    u32x4 v1 = *(const u32x4*)&Hb[(size_t)(r1 & 0x7FFFF) * 32 + q * 8];
    u32x4 v2 = *(const u32x4*)&Hb[(size_t)(r2 & 0x7FFFF) * 32 + q * 8];
    u32x4 v3 = *(const u32x4*)&Hb[(size_t)(r3 & 0x7FFFF) * 32 + q * 8];
    float f0 = __builtin_amdgcn_rcpf((float)(r0 >> 19));
    float f1 = __builtin_amdgcn_rcpf((float)(r1 >> 19));
    float f2 = __builtin_amdgcn_rcpf((float)(r2 >> 19));
    float f3 = __builtin_amdgcn_rcpf((float)(r3 >> 19));
    f32x2 s0 = {f0, f0}, s1 = {f1, f1}, s2v = {f2, f2}, s3 = {f3, f3};
    a0 += bfpair(v0[0]) * s0; a1 += bfpair(v0[1]) * s0;
    a2 += bfpair(v0[2]) * s0; a3 += bfpair(v0[3]) * s0;
    a0 += bfpair(v1[0]) * s1; a1 += bfpair(v1[1]) * s1;
    a2 += bfpair(v1[2]) * s1; a3 += bfpair(v1[3]) * s1;
    a0 += bfpair(v2[0]) * s2v; a1 += bfpair(v2[1]) * s2v;
    a2 += bfpair(v2[2]) * s2v; a3 += bfpair(v2[3]) * s2v;
    a0 += bfpair(v3[0]) * s3; a1 += bfpair(v3[1]) * s3;
    a2 += bfpair(v3[2]) * s3; a3 += bfpair(v3[3]) * s3;
  }
  for (; j < j1; j++) {
    unsigned r = erec[j];
    float sc = __builtin_amdgcn_rcpf((float)(r >> 19));
    f32x2 sc2 = {sc, sc};
    u32x4 v = *(const u32x4*)&Hb[(size_t)(r & 0x7FFFF) * 32 + q * 8];
    a0 += bfpair(v[0]) * sc2;
    a1 += bfpair(v[1]) * sc2;
    a2 += bfpair(v[2]) * sc2;
    a3 += bfpair(v[3]) * sc2;
  }
#pragma unroll
  for (int m = 4; m <= 8; m <<= 1) {
    a0[0] += __shfl_xor(a0[0], m); a0[1] += __shfl_xor(a0[1], m);
    a1[0] += __shfl_xor(a1[0], m); a1[1] += __shfl_xor(a1[1], m);
    a2[0] += __shfl_xor(a2[0], m); a2[1] += __shfl_xor(a2[1], m);
    a3[0] += __shfl_xor(a3[0], m); a3[1] += __shfl_xor(a3[1], m);
  }
  if (k == 0) {
    const float4* zr = (const float4*)&z2r[(size_t)w * 32 + q * 8];
    float4 r0 = zr[0], r1 = zr[1];
    uint4 st;
    st.x = pk2(r0.x + a0[0], r0.y + a0[1]);
    st.y = pk2(r0.z + a1[0], r0.w + a1[1]);
    st.z = pk2(r1.x + a2[0], r1.y + a2[1]);
    st.w = pk2(r1.z + a3[0], r1.w + a3[1]);
    *(uint4*)&z2b[(size_t)w * 32 + q * 8] = st;
  }
}

// MFMA decoder: one wave per 16 pred-edges. ef=[z2b[s],z2b[d]] (K=64) @ Wd1
// (bf16 B-frags, LDS) -> relu -> dot w2. A-frag gathered directly from z2b.
__global__ __launch_bounds__(256) void decoder_kernel(
    const ushort* __restrict__ z2b, const int* __restrict__ pe,
    const ushort* __restrict__ Bd1h, const float* __restrict__ bd1,
    const float* __restrict__ Wd2, const float* __restrict__ bd2,
    float* __restrict__ out, int P) {
  __shared__ int4 wsm[512];  // 4096 bf16 = 8 KB
  __shared__ float b1s[64], w2s[64];
  int tid = threadIdx.x;
  {
    const int4* g = (const int4*)Bd1h;
    for (int i = tid; i < 512; i += 256) wsm[i] = g[i];
    if (tid < 64) { b1s[tid] = bd1[tid]; w2s[tid] = Wd2[tid]; }
  }
  __syncthreads();
  const short* bsp = (const short*)wsm;
  int wv = tid >> 6, lane = tid & 63;
  int quad = lane >> 4, nn = lane & 15;
  int p0 = blockIdx.x * 64 + wv * 16;
  int p = min(p0 + nn, P - 1);  // A-row edge index = lane&15
  int s = pe[p], d = pe[P + p];
  bf16x8 a0 = *(const bf16x8*)&z2b[(size_t)s * 32 + quad * 8];  // k 0..31
  bf16x8 a1 = *(const bf16x8*)&z2b[(size_t)d * 32 + quad * 8];  // k 32..63
  f32x4 acc[4];
#pragma unroll
  for (int nt = 0; nt < 4; nt++) acc[nt] = (f32x4){0.f, 0.f, 0.f, 0.f};
#pragma unroll
  for (int nt = 0; nt < 4; nt++) {
    bf16x8 b0 = *(const bf16x8*)&bsp[((0 * 4 + nt) * 64 + lane) * 8];
    acc[nt] = __builtin_amdgcn_mfma_f32_16x16x32_bf16(a0, b0, acc[nt], 0, 0, 0);
    bf16x8 b1 = *(const bf16x8*)&bsp[((1 * 4 + nt) * 64 + lane) * 8];
    acc[nt] = __builtin_amdgcn_mfma_f32_16x16x32_bf16(a1, b1, acc[nt], 0, 0, 0);
  }
  // D: row(edge)=quad*4+rg, col=nt*16+nn. Per-lane partial over its 4 cols,
  // then reduce across the 16 nn-lanes of this quad.
  float part[4];
#pragma unroll
  for (int rg = 0; rg < 4; rg++) {
    float t = 0.f;
#pragma unroll
    for (int nt = 0; nt < 4; nt++) {
      int col = nt * 16 + nn;
      float h = fmaxf(acc[nt][rg] + b1s[col], 0.f);
      t += h * w2s[col];
    }
    part[rg] = t;
  }
#pragma unroll
  for (int m = 1; m <= 8; m <<= 1)
#pragma unroll
    for (int rg = 0; rg < 4; rg++) part[rg] += __shfl_xor(part[rg], m);
  if (nn == 0) {
    float base = bd2[0];
#pragma unroll
    for (int rg = 0; rg < 4; rg++) {
      int po = p0 + quad * 4 + rg;
      if (po < P) out[po] = part[rg] + base;
    }
  }
}

extern "C" void kernel_launch(void* const* d_in, const int* in_sizes, int n_in,
                              void* d_out, int out_size, void* d_ws, size_t ws_size,
                              hipStream_t stream) {
  const float* x     = (const float*)d_in[0];
  const int*   ei    = (const int*)d_in[1];
  const int*   et    = (const int*)d_in[2];
  const int*   pe    = (const int*)d_in[3];
  const float* W1    = (const float*)d_in[4];
  const float* root1 = (const float*)d_in[5];
  const float* b1    = (const float*)d_in[6];
  const float* W2    = (const float*)d_in[7];
  const float* root2 = (const float*)d_in[8];
  const float* b2    = (const float*)d_in[9];
  const float* Wd1   = (const float*)d_in[10];
  const float* bd1   = (const float*)d_in[11];
  const float* Wd2   = (const float*)d_in[12];
  const float* bd2   = (const float*)d_in[13];
  float* out = (float*)d_out;

  const int N = in_sizes[0] / 128;  // 100000
  const int E = in_sizes[2];        // 1600000
  const int P = in_sizes[3] / 2;    // 200000

  const int NBUCK = (N + 255) >> 8;   // 256-dst windows (<=511 for local scan)
  const int tile  = (E + 511) / 512;  // edges per partition block (512 tiles)

  // Workspace layout (float units; N%4==0 so kN offsets stay 16B-aligned):
  //   z1r:0..64N  z1b(bf16):64N..96N  z2r:96N..128N  z2b(bf16):128N..144N
  //   Hb(bf16):144N..240N  Bpack:240N..241N
  //   ints @241N: sd 2N | erec (E u32, slot 2E) | (unused 1024) | rowsum 1024
  //   | hist NBUCK*512 | rec E
  float* ws   = (float*)d_ws;
  float* z1r  = ws;
  ushort* z1b = (ushort*)(ws + (size_t)64 * N);
  float* z2r  = ws + (size_t)96 * N;
  ushort* z2b = (ushort*)(ws + (size_t)128 * N);
  ushort* Hb  = (ushort*)(ws + (size_t)144 * N);
  ushort* Bh1 = (ushort*)(ws + (size_t)240 * N);  // 32768
  ushort* Bl1 = Bh1 + 32768;                      // 32768
  ushort* Bh2 = Bl1 + 32768;                      // 8192
  ushort* Bl2 = Bh2 + 8192;                       // 8192
  ushort* Bd1h = Bl2 + 8192;                      // 4096
  int* ib      = (int*)(ws + (size_t)241 * N);
  int2* sd     = (int2*)ib;                       // N int2
  unsigned* erec = (unsigned*)(ib + 2 * (size_t)N);   // E u32 (slot holds 2E)
  int* rowsum  = ib + 2 * (size_t)N + 2 * (size_t)E + 1024;  // pad 1024
  int* hist    = rowsum + 1024;                   // NBUCK*512
  unsigned* rec = (unsigned*)(hist + (size_t)NBUCK * 512);  // E

  // gemm1 block slices riding on the CSR-chain dispatches (gemm1 depends only
  // on the packing done in dispatch 1; last slice completes before pull64).
  const int gb = (N + 63) / 64;  // 1563 gemm1 blocks total
  int s1 = min(gb, 400);
  int s3 = min(gb - s1, 500);
  int s4 = gb - s1 - s3;

  // --- CSR build (3 dispatches; scan_top folded into consumers) ---
  hist_pack_kernel<<<512 + 176, 256, 0, stream>>>(
      ei, hist, E, tile, NBUCK, W1, root1, Bh1, Bl1, W2, root2, Bh2, Bl2,
      Wd1, Bd1h);
  scan_rows_gemm_kernel<<<NBUCK + s1, 256, 0, stream>>>(
      hist, rowsum, NBUCK, 0, x, Bh1, Bl1, b1, Hb, z1r, N);
  part_scatter_gemm_kernel<<<512 + s3, 256, 0, stream>>>(
      ei, et, hist, rowsum, rec, E, tile, NBUCK, 512, s1,
      x, Bh1, Bl1, b1, Hb, z1r, N);
  bucket_build_gemm_kernel<<<NBUCK + s4, 256, 0, stream>>>(
      rec, rowsum, sd, erec, N, NBUCK, NBUCK, s1 + s3,
      x, Bh1, Bl1, b1, Hb, z1r);

  // --- layer 1 pull (gemm1 completed inside the chain dispatches) ---
  pull64_kernel<<<((size_t)N * 32 + 255) / 256, 256, 0, stream>>>(Hb, erec, sd, z1r, z1b, N);

  // --- layer 2: K=64 -> 32 (bf16 A, no split) ---
  mfma_gemm2_kernel<<<gb, 256, 0, stream>>>(z1b, Bh2, Bl2, b2, Hb, z2r, N);
  pull32_kernel<<<((size_t)N * 16 + 255) / 256, 256, 0, stream>>>(Hb, erec, sd, z2r, z2b, N);

  // --- decoder (MFMA) ---
  decoder_kernel<<<(P + 63) / 64, 256, 0, stream>>>(z2b, pe, Bd1h, bd1, Wd2, bd2, out, P);
}

// Round 11
// 287.150 us; speedup vs baseline: 1.0336x; 1.0336x over previous
//
#include <hip/hip_runtime.h>
#include <hip/hip_bf16.h>

// ---------------------------------------------------------------------------
// RGCN link predictor. Atomic-free CSR build + CSR-pull + bf16 MFMA GEMMs.
//   rgcn_conv(x) = x@root + b + sum_r segsum_dst( H_r[src] ) / max(cnt_r[dst],1)
//   Pulls: channel-exclusive lane groups + 4-way edge-split per node
//   (shfl_xor combine) + chunk-4 batched gather issue. erec packed to 4B
//   (row | cnt<<19); scale via v_rcp. Plain cached loads/stores.
//   CSR build: 2-level bucket sort by dst (256-dst windows), 256 edge tiles
//   (512 tiles regressed in R9: write amplification). R10: chunk-4 batched
//   load issue in hist/scatter/bucket loops — chain blocks run at 1 wave/SIMD
//   (zero TLP), so per-iteration exposed latency dominates; batching restores
//   ILP. scan_top folded into consumers. Layer-1 GEMM blocks ride along
//   inside the CSR-chain dispatches. 8 dispatches.
// ---------------------------------------------------------------------------

typedef short bf16x8 __attribute__((ext_vector_type(8)));
typedef float f32x4 __attribute__((ext_vector_type(4)));
typedef float f32x2 __attribute__((ext_vector_type(2)));
typedef unsigned u32x4 __attribute__((ext_vector_type(4)));

__device__ __forceinline__ unsigned short f2bf(float f) {
  union { float f; unsigned u; } x; x.f = f;
  unsigned r = x.u + 0x7FFF + ((x.u >> 16) & 1);  // RNE
  return (unsigned short)(r >> 16);
}
__device__ __forceinline__ float bf2f(unsigned short h) {
  union { unsigned u; float f; } x; x.u = ((unsigned)h) << 16;
  return x.f;
}
__device__ __forceinline__ f32x2 bfpair(unsigned u) {
  union { unsigned u; float f; } a, b;
  a.u = u << 16; b.u = u & 0xFFFF0000u;
  f32x2 r; r[0] = a.f; r[1] = b.f; return r;
}
__device__ __forceinline__ unsigned pk2(float a, float b) {
  return (unsigned)f2bf(a) | ((unsigned)f2bf(b) << 16);
}

// pack weights into MFMA B-fragment order, split hi/lo.
template <int K, int TN>
__device__ __forceinline__ void pack_one(
    int e, const float* __restrict__ W, const float* __restrict__ root,
    ushort* __restrict__ Bh, ushort* __restrict__ Bl) {
  int slab = e / (K * TN), r = e % (K * TN);
  int k = r / TN, n = r % TN;
  float v = (slab < 3) ? W[(size_t)slab * K * TN + k * TN + n] : root[(size_t)k * TN + n];
  int kc = k >> 5, quad = (k >> 3) & 3, j = k & 7, nt = n >> 4, nn = n & 15;
  int NTt = TN / 16;
  int didx = slab * K * TN + ((kc * NTt + nt) * 64 + quad * 16 + nn) * 8 + j;
  unsigned short h = f2bf(v);
  Bh[didx] = h;
  Bl[didx] = f2bf(v - bf2f(h));
}

// blocks 0..255: histogram of dst>>8 per tile (chunk-4 batched loads).
// blocks 256..431: weight packing (layer1, layer2, decoder Wd1).
__global__ __launch_bounds__(256) void hist_pack_kernel(
    const int* __restrict__ ei, int* __restrict__ hist, int E, int tile, int NBUCK,
    const float* __restrict__ W1, const float* __restrict__ root1,
    ushort* __restrict__ Bh1, ushort* __restrict__ Bl1,
    const float* __restrict__ W2, const float* __restrict__ root2,
    ushort* __restrict__ Bh2, ushort* __restrict__ Bl2,
    const float* __restrict__ Wd1, ushort* __restrict__ Bd1h) {
  int tid = threadIdx.x;
  if (blockIdx.x >= 256) {
    int e = (blockIdx.x - 256) * 256 + tid;
    if (e < 32768) {
      pack_one<128, 64>(e, W1, root1, Bh1, Bl1);
    } else if (e < 32768 + 8192) {
      pack_one<64, 32>(e - 32768, W2, root2, Bh2, Bl2);
    } else if (e < 32768 + 8192 + 4096) {
      int r = e - 32768 - 8192;          // Wd1: K=64, TN=64, single slab
      int k = r >> 6, n = r & 63;
      int kc = k >> 5, quad = (k >> 3) & 3, j = k & 7, nt = n >> 4, nn = n & 15;
      Bd1h[((kc * 4 + nt) * 64 + quad * 16 + nn) * 8 + j] = f2bf(Wd1[k * 64 + n]);
    }
    return;
  }
  __shared__ int lh[512];
  for (int i = tid; i < 512; i += 256) lh[i] = 0;
  __syncthreads();
  int e0 = blockIdx.x * tile, e1 = min(E, e0 + tile);
  int e = e0 + tid;
  for (; e + 768 < e1; e += 1024) {
    int d0 = ei[E + e], d1 = ei[E + e + 256];
    int d2 = ei[E + e + 512], d3 = ei[E + e + 768];
    atomicAdd(&lh[d0 >> 8], 1); atomicAdd(&lh[d1 >> 8], 1);
    atomicAdd(&lh[d2 >> 8], 1); atomicAdd(&lh[d3 >> 8], 1);
  }
  for (; e < e1; e += 256) atomicAdd(&lh[ei[E + e] >> 8], 1);
  __syncthreads();
  for (int i = tid; i < NBUCK; i += 256) hist[i * 256 + blockIdx.x] = lh[i];
}

// ---------------------------------------------------------------------------
// Layer-1 split-bf16 MFMA GEMM as a device body so its blocks can ride along
// inside the CSR-chain dispatches. Block = 4 waves x 16 rows = 64 rows.
// H slabs (0-2): Ah*Bh + Al*Bh, bf16 out. z slab (3): + Ah*Bl, fp32 + bias.
// ---------------------------------------------------------------------------
__device__ __forceinline__ void gemm1_body(
    int bid, int4* __restrict__ bsm,
    const float* __restrict__ A, const ushort* __restrict__ Bh,
    const ushort* __restrict__ Bl, const float* __restrict__ bias,
    ushort* __restrict__ Hb, float* __restrict__ z, int n) {
  constexpr int K = 128, TN = 64;
  constexpr int KC = K / 32;       // 4
  constexpr int NTt = TN / 16;     // 4
  constexpr int HALF = K * TN / 8; // 1024 int4 = 16 KB per half
  const int tid = threadIdx.x;
  const int w = tid >> 6, lane = tid & 63;
  const int quad = lane >> 4, nn = lane & 15;
  const int rowBase = bid * 64 + w * 16;

  int row = rowBase + nn;
  if (row >= n) row = n - 1;  // clamp; stores are guarded
  const float* ap = &A[(size_t)row * K + quad * 8];
  bf16x8 ah[KC], al[KC];
#pragma unroll
  for (int kc = 0; kc < KC; kc++) {
    float4 f0 = *(const float4*)(ap + kc * 32);
    float4 f1 = *(const float4*)(ap + kc * 32 + 4);
    float f[8] = {f0.x, f0.y, f0.z, f0.w, f1.x, f1.y, f1.z, f1.w};
#pragma unroll
    for (int j = 0; j < 8; j++) {
      unsigned short h = f2bf(f[j]);
      ah[kc][j] = (short)h;
      al[kc][j] = (short)f2bf(f[j] - bf2f(h));
    }
  }

  const short* bsp = (const short*)bsm;

#pragma unroll 1
  for (int slab = 0; slab < 4; slab++) {
    __syncthreads();
    {
      const int4* gh = (const int4*)(Bh + (size_t)slab * K * TN);
      for (int i = tid; i < HALF; i += 256) bsm[i] = gh[i];
      if (slab == 3) {
        const int4* gl = (const int4*)(Bl + (size_t)slab * K * TN);
        for (int i = tid; i < HALF; i += 256) bsm[HALF + i] = gl[i];
      }
    }
    __syncthreads();

    f32x4 acc[NTt];
#pragma unroll
    for (int j = 0; j < NTt; j++) acc[j] = (f32x4){0.f, 0.f, 0.f, 0.f};

#pragma unroll
    for (int kc = 0; kc < KC; kc++) {
#pragma unroll
      for (int nt = 0; nt < NTt; nt++) {
        bf16x8 b = *(const bf16x8*)&bsp[((kc * NTt + nt) * 64 + lane) * 8];
        acc[nt] = __builtin_amdgcn_mfma_f32_16x16x32_bf16(ah[kc], b, acc[nt], 0, 0, 0);
        acc[nt] = __builtin_amdgcn_mfma_f32_16x16x32_bf16(al[kc], b, acc[nt], 0, 0, 0);
      }
    }
    if (slab == 3) {
#pragma unroll
      for (int kc = 0; kc < KC; kc++) {
#pragma unroll
        for (int nt = 0; nt < NTt; nt++) {
          bf16x8 b = *(const bf16x8*)&bsp[(HALF * 8) + ((kc * NTt + nt) * 64 + lane) * 8];
          acc[nt] = __builtin_amdgcn_mfma_f32_16x16x32_bf16(ah[kc], b, acc[nt], 0, 0, 0);
        }
      }
    }

    int grow0 = rowBase + quad * 4;
#pragma unroll
    for (int nt = 0; nt < NTt; nt++) {
      int col = nt * 16 + nn;
#pragma unroll
      for (int rg = 0; rg < 4; rg++) {
        int grow = grow0 + rg;
        if (grow < n) {
          float v = acc[nt][rg];
          if (slab == 3) z[(size_t)grow * TN + col] = v + bias[col];
          else Hb[((size_t)slab * n + grow) * TN + col] = f2bf(v);
        }
      }
    }
  }
}

// --- fused chain kernels: blockIdx < nChain -> chain work, else gemm1 slice.
// All share a 32 KB LDS buffer (gemm needs 2*HALF int4; chain aliases ints).

// parallel scan of each bucket row (256 entries) -> exclusive, + rowsum
__global__ __launch_bounds__(256, 4) void scan_rows_gemm_kernel(
    int* __restrict__ hist, int* __restrict__ rowsum, int nChain, int gemmBase,
    const float* __restrict__ A, const ushort* __restrict__ Bh,
    const ushort* __restrict__ Bl, const float* __restrict__ bias,
    ushort* __restrict__ Hb, float* __restrict__ z, int n) {
  __shared__ int4 smem[2048];
  if ((int)blockIdx.x >= nChain) {
    gemm1_body(gemmBase + (int)blockIdx.x - nChain, smem, A, Bh, Bl, bias, Hb, z, n);
    return;
  }
  int* sA = (int*)smem;
  int* sB = sA + 256;
  int t = threadIdx.x;
  int* row = hist + blockIdx.x * 256;
  int v = row[t];
  sA[t] = v;
  __syncthreads();
  int* src = sA; int* dst = sB;
  for (int off = 1; off < 256; off <<= 1) {
    int x = src[t];
    if (t >= off) x += src[t - off];
    dst[t] = x;
    __syncthreads();
    int* tmp = src; src = dst; dst = tmp;
  }
  row[t] = src[t] - v;
  if (t == 255) rowsum[blockIdx.x] = src[255];
}

// scatter edges into coarse buckets. Chunk-4 batched load issue (12
// independent loads ahead of 4 atomic+store pairs — chain runs at ~1
// wave/SIMD so ILP is the only latency hiding). rowbase via local LDS scan.
__global__ __launch_bounds__(256, 4) void part_scatter_gemm_kernel(
    const int* __restrict__ ei, const int* __restrict__ et,
    const int* __restrict__ hist, const int* __restrict__ rowsum,
    unsigned* __restrict__ rec, int E, int tile, int NBUCK,
    int nChain, int gemmBase,
    const float* __restrict__ A, const ushort* __restrict__ Bh,
    const ushort* __restrict__ Bl, const float* __restrict__ bias,
    ushort* __restrict__ Hb, float* __restrict__ z, int n) {
  __shared__ int4 smem[2048];
  if ((int)blockIdx.x >= nChain) {
    gemm1_body(gemmBase + (int)blockIdx.x - nChain, smem, A, Bh, Bl, bias, Hb, z, n);
    return;
  }
  int* sA = (int*)smem;      // 256
  int* sB = sA + 256;        // 256
  int* rb = sB + 256;        // 512 rowbase
  int* ctr = rb + 512;       // 512
  int t = threadIdx.x;
  // local exclusive scan of rowsum (2 elems/thread, NBUCK <= 511)
  int e0 = 2 * t, e1 = 2 * t + 1;
  int v0 = (e0 < NBUCK) ? rowsum[e0] : 0;
  int v1 = (e1 < NBUCK) ? rowsum[e1] : 0;
  int v = v0 + v1;
  sA[t] = v;
  __syncthreads();
  int* src = sA; int* dst = sB;
  for (int off = 1; off < 256; off <<= 1) {
    int x = src[t];
    if (t >= off) x += src[t - off];
    dst[t] = x;
    __syncthreads();
    int* tmp = src; src = dst; dst = tmp;
  }
  int excl = src[t] - v;
  rb[e0] = excl;
  rb[e1] = excl + v0;
  __syncthreads();
  for (int i = t; i < NBUCK; i += 256)
    ctr[i] = hist[i * 256 + blockIdx.x] + rb[i];
  __syncthreads();
  int e0g = blockIdx.x * tile, e1g = min(E, e0g + tile);
  int e = e0g + t;
  for (; e + 768 < e1g; e += 1024) {
    int s0 = ei[e],       s1 = ei[e + 256],     s2 = ei[e + 512],     s3 = ei[e + 768];
    int d0 = ei[E + e],   d1 = ei[E + e + 256], d2 = ei[E + e + 512], d3 = ei[E + e + 768];
    int t0 = et[e],       t1 = et[e + 256],     t2 = et[e + 512],     t3 = et[e + 768];
    int p0 = atomicAdd(&ctr[d0 >> 8], 1);
    rec[p0] = (unsigned)(s0 | (t0 << 20) | ((d0 & 255) << 22));
    int p1 = atomicAdd(&ctr[d1 >> 8], 1);
    rec[p1] = (unsigned)(s1 | (t1 << 20) | ((d1 & 255) << 22));
    int p2 = atomicAdd(&ctr[d2 >> 8], 1);
    rec[p2] = (unsigned)(s2 | (t2 << 20) | ((d2 & 255) << 22));
    int p3 = atomicAdd(&ctr[d3 >> 8], 1);
    rec[p3] = (unsigned)(s3 | (t3 << 20) | ((d3 & 255) << 22));
  }
  for (; e < e1g; e += 256) {
    int s = ei[e];
    int d = ei[E + e];
    int rt = et[e];
    int p = atomicAdd(&ctr[d >> 8], 1);
    rec[p] = (unsigned)(s | (rt << 20) | ((d & 255) << 22));
  }
}

// one block per 256-dst window: per-(rel,dst) counts, sd, and final dst-grouped
// erec = (row | cnt<<19) 4B packed. rowbase via local rowsum scan. Chunk-4
// batched rec loads in both passes.
__global__ __launch_bounds__(256, 4) void bucket_build_gemm_kernel(
    const unsigned* __restrict__ rec, const int* __restrict__ rowsum,
    int2* __restrict__ sd, unsigned* __restrict__ erec, int N, int NBUCK,
    int nChain, int gemmBase,
    const float* __restrict__ A, const ushort* __restrict__ Bh,
    const ushort* __restrict__ Bl, const float* __restrict__ bias,
    ushort* __restrict__ Hb, float* __restrict__ z) {
  __shared__ int4 smem[2048];
  if ((int)blockIdx.x >= nChain) {
    gemm1_body(gemmBase + (int)blockIdx.x - nChain, smem, A, Bh, Bl, bias, Hb, z, N);
    return;
  }
  int* c3 = (int*)smem;       // 768
  int* sA = c3 + 768;         // 256
  int* sB = sA + 256;         // 256
  int* cur = sB + 256;        // 256
  int* rb = cur + 256;        // 512 rowbase
  int tid = threadIdx.x;
  // local exclusive scan of rowsum -> rb (rb[NBUCK] = E automatically)
  {
    int e0 = 2 * tid, e1 = 2 * tid + 1;
    int v0 = (e0 < NBUCK) ? rowsum[e0] : 0;
    int v1 = (e1 < NBUCK) ? rowsum[e1] : 0;
    int v = v0 + v1;
    sA[tid] = v;
    __syncthreads();
    int* src = sA; int* dst = sB;
    for (int off = 1; off < 256; off <<= 1) {
      int x = src[tid];
      if (tid >= off) x += src[tid - off];
      dst[tid] = x;
      __syncthreads();
      int* tmp = src; src = dst; dst = tmp;
    }
    int excl = src[tid] - v;
    rb[e0] = excl;
    rb[e1] = excl + v0;
    __syncthreads();
  }
  int dstBase = blockIdx.x << 8;
  int bs = rb[blockIdx.x], be = rb[blockIdx.x + 1];
  for (int i = tid; i < 768; i += 256) c3[i] = 0;
  __syncthreads();
  int i = bs + tid;
  for (; i + 768 < be; i += 1024) {
    unsigned r0 = rec[i], r1 = rec[i + 256], r2 = rec[i + 512], r3 = rec[i + 768];
    atomicAdd(&c3[((r0 >> 20) & 3) * 256 + (r0 >> 22)], 1);
    atomicAdd(&c3[((r1 >> 20) & 3) * 256 + (r1 >> 22)], 1);
    atomicAdd(&c3[((r2 >> 20) & 3) * 256 + (r2 >> 22)], 1);
    atomicAdd(&c3[((r3 >> 20) & 3) * 256 + (r3 >> 22)], 1);
  }
  for (; i < be; i += 256) {
    unsigned r = rec[i];
    atomicAdd(&c3[((r >> 20) & 3) * 256 + (r >> 22)], 1);
  }
  __syncthreads();
  int dgv = c3[tid] + c3[256 + tid] + c3[512 + tid];
  sA[tid] = dgv;
  __syncthreads();
  int* src = sA; int* dst = sB;
  for (int off = 1; off < 256; off <<= 1) {
    int x = src[tid];
    if (tid >= off) x += src[tid - off];
    dst[tid] = x;
    __syncthreads();
    int* tmp = src; src = dst; dst = tmp;
  }
  int excl = src[tid] - dgv;
  cur[tid] = bs + excl;
  if (dstBase + tid < N) sd[dstBase + tid] = make_int2(bs + excl, dgv);
  __syncthreads();
  i = bs + tid;
  for (; i + 768 < be; i += 1024) {
    unsigned r0 = rec[i], r1 = rec[i + 256], r2 = rec[i + 512], r3 = rec[i + 768];
    {
      int dloc = r0 >> 22, rt = (r0 >> 20) & 3;
      int p = atomicAdd(&cur[dloc], 1);
      unsigned cnt = (unsigned)c3[rt * 256 + dloc];
      erec[p] = (unsigned)(rt * N + (int)(r0 & 0xFFFFF)) | (cnt << 19);
    }
    {
      int dloc = r1 >> 22, rt = (r1 >> 20) & 3;
      int p = atomicAdd(&cur[dloc], 1);
      unsigned cnt = (unsigned)c3[rt * 256 + dloc];
      erec[p] = (unsigned)(rt * N + (int)(r1 & 0xFFFFF)) | (cnt << 19);
    }
    {
      int dloc = r2 >> 22, rt = (r2 >> 20) & 3;
      int p = atomicAdd(&cur[dloc], 1);
      unsigned cnt = (unsigned)c3[rt * 256 + dloc];
      erec[p] = (unsigned)(rt * N + (int)(r2 & 0xFFFFF)) | (cnt << 19);
    }
    {
      int dloc = r3 >> 22, rt = (r3 >> 20) & 3;
      int p = atomicAdd(&cur[dloc], 1);
      unsigned cnt = (unsigned)c3[rt * 256 + dloc];
      erec[p] = (unsigned)(rt * N + (int)(r3 & 0xFFFFF)) | (cnt << 19);
    }
  }
  for (; i < be; i += 256) {
    unsigned r = rec[i];
    int dloc = r >> 22;
    int rt = (r >> 20) & 3;
    int p = atomicAdd(&cur[dloc], 1);
    unsigned cnt = (unsigned)c3[rt * 256 + dloc];  // >=1, < 2^13
    erec[p] = (unsigned)(rt * N + (int)(r & 0xFFFFF)) | (cnt << 19);
  }
}

// Layer-2 pure-bf16 MFMA GEMM (A = z1b bf16, no split). K=64, TN=32.
__global__ __launch_bounds__(256, 4) void mfma_gemm2_kernel(
    const ushort* __restrict__ Ab, const ushort* __restrict__ Bh,
    const ushort* __restrict__ Bl, const float* __restrict__ bias,
    ushort* __restrict__ Hb, float* __restrict__ z2r, int n) {
  constexpr int KC = 2, NTt = 2, HALF = 64 * 32 / 8;
  __shared__ int4 bsm[2 * HALF];
  const int tid = threadIdx.x;
  const int w = tid >> 6, lane = tid & 63;
  const int quad = lane >> 4, nn = lane & 15;
  const int rowBase = blockIdx.x * 64 + w * 16;

  int row = rowBase + nn;
  if (row >= n) row = n - 1;
  const ushort* ap = &Ab[(size_t)row * 64 + quad * 8];
  bf16x8 ah[KC];
  ah[0] = *(const bf16x8*)(ap);
  ah[1] = *(const bf16x8*)(ap + 32);

  const short* bsp = (const short*)bsm;

#pragma unroll 1
  for (int slab = 0; slab < 4; slab++) {
    __syncthreads();
    {
      const int4* gh = (const int4*)(Bh + (size_t)slab * 64 * 32);
      for (int i = tid; i < HALF; i += 256) bsm[i] = gh[i];
      if (slab == 3) {
        const int4* gl = (const int4*)(Bl + (size_t)slab * 64 * 32);
        for (int i = tid; i < HALF; i += 256) bsm[HALF + i] = gl[i];
      }
    }
    __syncthreads();

    f32x4 acc[NTt];
#pragma unroll
    for (int j = 0; j < NTt; j++) acc[j] = (f32x4){0.f, 0.f, 0.f, 0.f};

#pragma unroll
    for (int kc = 0; kc < KC; kc++) {
#pragma unroll
      for (int nt = 0; nt < NTt; nt++) {
        bf16x8 b = *(const bf16x8*)&bsp[((kc * NTt + nt) * 64 + lane) * 8];
        acc[nt] = __builtin_amdgcn_mfma_f32_16x16x32_bf16(ah[kc], b, acc[nt], 0, 0, 0);
      }
    }
    if (slab == 3) {
#pragma unroll
      for (int kc = 0; kc < KC; kc++) {
#pragma unroll
        for (int nt = 0; nt < NTt; nt++) {
          bf16x8 b = *(const bf16x8*)&bsp[(HALF * 8) + ((kc * NTt + nt) * 64 + lane) * 8];
          acc[nt] = __builtin_amdgcn_mfma_f32_16x16x32_bf16(ah[kc], b, acc[nt], 0, 0, 0);
        }
      }
    }

    int grow0 = rowBase + quad * 4;
#pragma unroll
    for (int nt = 0; nt < NTt; nt++) {
      int col = nt * 16 + nn;
#pragma unroll
      for (int rg = 0; rg < 4; rg++) {
        int grow = grow0 + rg;
        if (grow < n) {
          float v = acc[nt][rg];
          if (slab == 3) z2r[(size_t)grow * 32 + col] = v + bias[col];
          else Hb[((size_t)slab * n + grow) * 32 + col] = f2bf(v);
        }
      }
    }
  }
}

// ---- pull, C=64: 32 lanes/node = 8 channel-lanes x 4 edge-quarters.
// Chunk-4 batched issue; 4B erec (row|cnt<<19), v_rcp scale; cached loads.
__global__ __launch_bounds__(256) void pull64_kernel(
    const ushort* __restrict__ Hb, const unsigned* __restrict__ erec,
    const int2* __restrict__ sd, const float* __restrict__ z1r,
    ushort* __restrict__ z1b, int N) {
  int t = blockIdx.x * 256 + threadIdx.x;
  int w = t >> 5;  // node
  if (w >= N) return;
  int q = threadIdx.x & 7;         // channel group (8 ch = 16B)
  int k = (threadIdx.x >> 3) & 3;  // edge quarter
  int2 s2 = sd[w];
  int j0 = s2.x + ((s2.y * k) >> 2);
  int j1 = s2.x + ((s2.y * (k + 1)) >> 2);
  f32x2 a0 = {0.f, 0.f}, a1 = a0, a2 = a0, a3 = a0;
  int j = j0;
  for (; j + 4 <= j1; j += 4) {
    unsigned r0 = erec[j], r1 = erec[j + 1], r2 = erec[j + 2], r3 = erec[j + 3];
    u32x4 v0 = *(const u32x4*)&Hb[(size_t)(r0 & 0x7FFFF) * 64 + q * 8];
    u32x4 v1 = *(const u32x4*)&Hb[(size_t)(r1 & 0x7FFFF) * 64 + q * 8];
    u32x4 v2 = *(const u32x4*)&Hb[(size_t)(r2 & 0x7FFFF) * 64 + q * 8];
    u32x4 v3 = *(const u32x4*)&Hb[(size_t)(r3 & 0x7FFFF) * 64 + q * 8];
    float f0 = __builtin_amdgcn_rcpf((float)(r0 >> 19));
    float f1 = __builtin_amdgcn_rcpf((float)(r1 >> 19));
    float f2 = __builtin_amdgcn_rcpf((float)(r2 >> 19));
    float f3 = __builtin_amdgcn_rcpf((float)(r3 >> 19));
    f32x2 s0 = {f0, f0}, s1 = {f1, f1}, s2v = {f2, f2}, s3 = {f3, f3};
    a0 += bfpair(v0[0]) * s0; a1 += bfpair(v0[1]) * s0;
    a2 += bfpair(v0[2]) * s0; a3 += bfpair(v0[3]) * s0;
    a0 += bfpair(v1[0]) * s1; a1 += bfpair(v1[1]) * s1;
    a2 += bfpair(v1[2]) * s1; a3 += bfpair(v1[3]) * s1;
    a0 += bfpair(v2[0]) * s2v; a1 += bfpair(v2[1]) * s2v;
    a2 += bfpair(v2[2]) * s2v; a3 += bfpair(v2[3]) * s2v;
    a0 += bfpair(v3[0]) * s3; a1 += bfpair(v3[1]) * s3;
    a2 += bfpair(v3[2]) * s3; a3 += bfpair(v3[3]) * s3;
  }
  for (; j < j1; j++) {
    unsigned r = erec[j];
    float sc = __builtin_amdgcn_rcpf((float)(r >> 19));
    f32x2 sc2 = {sc, sc};
    u32x4 v = *(const u32x4*)&Hb[(size_t)(r & 0x7FFFF) * 64 + q * 8];
    a0 += bfpair(v[0]) * sc2;
    a1 += bfpair(v[1]) * sc2;
    a2 += bfpair(v[2]) * sc2;
    a3 += bfpair(v[3]) * sc2;
  }
  // combine the 4 quarters (lanes differing in tid bits 3-4)
#pragma unroll
  for (int m = 8; m <= 16; m <<= 1) {
    a0[0] += __shfl_xor(a0[0], m); a0[1] += __shfl_xor(a0[1], m);
    a1[0] += __shfl_xor(a1[0], m); a1[1] += __shfl_xor(a1[1], m);
    a2[0] += __shfl_xor(a2[0], m); a2[1] += __shfl_xor(a2[1], m);
    a3[0] += __shfl_xor(a3[0], m); a3[1] += __shfl_xor(a3[1], m);
  }
  if (k == 0) {
    const float4* zr = (const float4*)&z1r[(size_t)w * 64 + q * 8];
    float4 r0 = zr[0], r1 = zr[1];
    uint4 st;
    st.x = pk2(fmaxf(r0.x + a0[0], 0.f), fmaxf(r0.y + a0[1], 0.f));
    st.y = pk2(fmaxf(r0.z + a1[0], 0.f), fmaxf(r0.w + a1[1], 0.f));
    st.z = pk2(fmaxf(r1.x + a2[0], 0.f), fmaxf(r1.y + a2[1], 0.f));
    st.w = pk2(fmaxf(r1.z + a3[0], 0.f), fmaxf(r1.w + a3[1], 0.f));
    *(uint4*)&z1b[(size_t)w * 64 + q * 8] = st;
  }
}

// ---- pull, C=32: 16 lanes/node = 4 channel-lanes x 4 edge-quarters.
// Chunk-4 batched issue; 4B erec; shfl_xor (4,8). No ReLU.
__global__ __launch_bounds__(256) void pull32_kernel(
    const ushort* __restrict__ Hb, const unsigned* __restrict__ erec,
    const int2* __restrict__ sd, const float* __restrict__ z2r,
    ushort* __restrict__ z2b, int N) {
  int t = blockIdx.x * 256 + threadIdx.x;
  int w = t >> 4;  // node
  if (w >= N) return;
  int q = threadIdx.x & 3;         // channel group
  int k = (threadIdx.x >> 2) & 3;  // edge quarter
  int2 s2 = sd[w];
  int j0 = s2.x + ((s2.y * k) >> 2);
  int j1 = s2.x + ((s2.y * (k + 1)) >> 2);
  f32x2 a0 = {0.f, 0.f}, a1 = a0, a2 = a0, a3 = a0;
  int j = j0;
  for (; j + 4 <= j1; j += 4) {
    unsigned r0 = erec[j], r1 = erec[j + 1], r2 = erec[j + 2], r3 = erec[j + 3];
    u32x4 v0 = *(const u32x4*)&Hb[(size_t)(r0 & 0x7FFFF) * 32 + q * 8];
    u32x4 v1 = *(const u32x4*)&Hb[(size_t)(r1 & 0x7FFFF) * 32 + q * 8];
    u32x4 v2 = *(const u32x4*)&Hb[(size_t)(r2 & 0x7FFFF) * 32 + q * 8];
    u32x4 v3 = *(const u32x4*)&Hb[(size_t)(r3 & 0x7FFFF) * 32 + q * 8];
    float f0 = __builtin_amdgcn_rcpf((float)(r0 >> 19));
    float f1 = __builtin_amdgcn_rcpf((float)(r1 >> 19));
    float f2 = __builtin_amdgcn_rcpf((float)(r2 >> 19));
    float f3 = __builtin_amdgcn_rcpf((float)(r3 >> 19));
    f32x2 s0 = {f0, f0}, s1 = {f1, f1}, s2v = {f2, f2}, s3 = {f3, f3};
    a0 += bfpair(v0[0]) * s0; a1 += bfpair(v0[1]) * s0;
    a2 += bfpair(v0[2]) * s0; a3 += bfpair(v0[3]) * s0;
    a0 += bfpair(v1[0]) * s1; a1 += bfpair(v1[1]) * s1;
    a2 += bfpair(v1[2]) * s1; a3 += bfpair(v1[3]) * s1;
    a0 += bfpair(v2[0]) * s2v; a1 += bfpair(v2[1]) * s2v;
    a2 += bfpair(v2[2]) * s2v; a3 += bfpair(v2[3]) * s2v;
    a0 += bfpair(v3[0]) * s3; a1 += bfpair(v3[1]) * s3;
    a2 += bfpair(v3[2]) * s3; a3 += bfpair(v3[3]) * s3;
  }
  for (; j < j1; j++) {
    unsigned r = erec[j];
    float sc = __builtin_amdgcn_rcpf((float)(r >> 19));
    f32x2 sc2 = {sc, sc};
    u32x4 v = *(const u32x4*)&Hb[(size_t)(r & 0x7FFFF) * 32 + q * 8];
    a0 += bfpair(v[0]) * sc2;
    a1 += bfpair(v[1]) * sc2;
    a2 += bfpair(v[2]) * sc2;
    a3 += bfpair(v[3]) * sc2;
  }
#pragma unroll
  for (int m = 4; m <= 8; m <<= 1) {
    a0[0] += __shfl_xor(a0[0], m); a0[1] += __shfl_xor(a0[1], m);
    a1[0] += __shfl_xor(a1[0], m); a1[1] += __shfl_xor(a1[1], m);
    a2[0] += __shfl_xor(a2[0], m); a2[1] += __shfl_xor(a2[1], m);
    a3[0] += __shfl_xor(a3[0], m); a3[1] += __shfl_xor(a3[1], m);
  }
  if (k == 0) {
    const float4* zr = (const float4*)&z2r[(size_t)w * 32 + q * 8];
    float4 r0 = zr[0], r1 = zr[1];
    uint4 st;
    st.x = pk2(r0.x + a0[0], r0.y + a0[1]);
    st.y = pk2(r0.z + a1[0], r0.w + a1[1]);
    st.z = pk2(r1.x + a2[0], r1.y + a2[1]);
    st.w = pk2(r1.z + a3[0], r1.w + a3[1]);
    *(uint4*)&z2b[(size_t)w * 32 + q * 8] = st;
  }
}

// MFMA decoder: one wave per 16 pred-edges. ef=[z2b[s],z2b[d]] (K=64) @ Wd1
// (bf16 B-frags, LDS) -> relu -> dot w2. A-frag gathered directly from z2b.
__global__ __launch_bounds__(256) void decoder_kernel(
    const ushort* __restrict__ z2b, const int* __restrict__ pe,
    const ushort* __restrict__ Bd1h, const float* __restrict__ bd1,
    const float* __restrict__ Wd2, const float* __restrict__ bd2,
    float* __restrict__ out, int P) {
  __shared__ int4 wsm[512];  // 4096 bf16 = 8 KB
  __shared__ float b1s[64], w2s[64];
  int tid = threadIdx.x;
  {
    const int4* g = (const int4*)Bd1h;
    for (int i = tid; i < 512; i += 256) wsm[i] = g[i];
    if (tid < 64) { b1s[tid] = bd1[tid]; w2s[tid] = Wd2[tid]; }
  }
  __syncthreads();
  const short* bsp = (const short*)wsm;
  int wv = tid >> 6, lane = tid & 63;
  int quad = lane >> 4, nn = lane & 15;
  int p0 = blockIdx.x * 64 + wv * 16;
  int p = min(p0 + nn, P - 1);  // A-row edge index = lane&15
  int s = pe[p], d = pe[P + p];
  bf16x8 a0 = *(const bf16x8*)&z2b[(size_t)s * 32 + quad * 8];  // k 0..31
  bf16x8 a1 = *(const bf16x8*)&z2b[(size_t)d * 32 + quad * 8];  // k 32..63
  f32x4 acc[4];
#pragma unroll
  for (int nt = 0; nt < 4; nt++) acc[nt] = (f32x4){0.f, 0.f, 0.f, 0.f};
#pragma unroll
  for (int nt = 0; nt < 4; nt++) {
    bf16x8 b0 = *(const bf16x8*)&bsp[((0 * 4 + nt) * 64 + lane) * 8];
    acc[nt] = __builtin_amdgcn_mfma_f32_16x16x32_bf16(a0, b0, acc[nt], 0, 0, 0);
    bf16x8 b1 = *(const bf16x8*)&bsp[((1 * 4 + nt) * 64 + lane) * 8];
    acc[nt] = __builtin_amdgcn_mfma_f32_16x16x32_bf16(a1, b1, acc[nt], 0, 0, 0);
  }
  // D: row(edge)=quad*4+rg, col=nt*16+nn. Per-lane partial over its 4 cols,
  // then reduce across the 16 nn-lanes of this quad.
  float part[4];
#pragma unroll
  for (int rg = 0; rg < 4; rg++) {
    float t = 0.f;
#pragma unroll
    for (int nt = 0; nt < 4; nt++) {
      int col = nt * 16 + nn;
      float h = fmaxf(acc[nt][rg] + b1s[col], 0.f);
      t += h * w2s[col];
    }
    part[rg] = t;
  }
#pragma unroll
  for (int m = 1; m <= 8; m <<= 1)
#pragma unroll
    for (int rg = 0; rg < 4; rg++) part[rg] += __shfl_xor(part[rg], m);
  if (nn == 0) {
    float base = bd2[0];
#pragma unroll
    for (int rg = 0; rg < 4; rg++) {
      int po = p0 + quad * 4 + rg;
      if (po < P) out[po] = part[rg] + base;
    }
  }
}

extern "C" void kernel_launch(void* const* d_in, const int* in_sizes, int n_in,
                              void* d_out, int out_size, void* d_ws, size_t ws_size,
                              hipStream_t stream) {
  const float* x     = (const float*)d_in[0];
  const int*   ei    = (const int*)d_in[1];
  const int*   et    = (const int*)d_in[2];
  const int*   pe    = (const int*)d_in[3];
  const float* W1    = (const float*)d_in[4];
  const float* root1 = (const float*)d_in[5];
  const float* b1    = (const float*)d_in[6];
  const float* W2    = (const float*)d_in[7];
  const float* root2 = (const float*)d_in[8];
  const float* b2    = (const float*)d_in[9];
  const float* Wd1   = (const float*)d_in[10];
  const float* bd1   = (const float*)d_in[11];
  const float* Wd2   = (const float*)d_in[12];
  const float* bd2   = (const float*)d_in[13];
  float* out = (float*)d_out;

  const int N = in_sizes[0] / 128;  // 100000
  const int E = in_sizes[2];        // 1600000
  const int P = in_sizes[3] / 2;    // 200000

  const int NBUCK = (N + 255) >> 8;   // 256-dst windows (<=511 for local scan)
  const int tile  = (E + 255) / 256;  // edges per partition block (256 tiles)

  // Workspace layout (float units; N%4==0 so kN offsets stay 16B-aligned):
  //   z1r:0..64N  z1b(bf16):64N..96N  z2r:96N..128N  z2b(bf16):128N..144N
  //   Hb(bf16):144N..240N  Bpack:240N..241N
  //   ints @241N: sd 2N | erec (E u32, slot 2E) | (unused 1024) | rowsum 1024
  //   | hist NBUCK*256 | rec E
  float* ws   = (float*)d_ws;
  float* z1r  = ws;
  ushort* z1b = (ushort*)(ws + (size_t)64 * N);
  float* z2r  = ws + (size_t)96 * N;
  ushort* z2b = (ushort*)(ws + (size_t)128 * N);
  ushort* Hb  = (ushort*)(ws + (size_t)144 * N);
  ushort* Bh1 = (ushort*)(ws + (size_t)240 * N);  // 32768
  ushort* Bl1 = Bh1 + 32768;                      // 32768
  ushort* Bh2 = Bl1 + 32768;                      // 8192
  ushort* Bl2 = Bh2 + 8192;                       // 8192
  ushort* Bd1h = Bl2 + 8192;                      // 4096
  int* ib      = (int*)(ws + (size_t)241 * N);
  int2* sd     = (int2*)ib;                       // N int2
  unsigned* erec = (unsigned*)(ib + 2 * (size_t)N);   // E u32 (slot holds 2E)
  int* rowsum  = ib + 2 * (size_t)N + 2 * (size_t)E + 1024;  // pad 1024
  int* hist    = rowsum + 1024;                   // NBUCK*256
  unsigned* rec = (unsigned*)(hist + (size_t)NBUCK * 256);  // E

  // gemm1 block slices riding on the CSR-chain dispatches (gemm1 depends only
  // on the packing done in dispatch 1; last slice completes before pull64).
  const int gb = (N + 63) / 64;  // 1563 gemm1 blocks total
  int s1 = min(gb, 400);
  int s3 = min(gb - s1, 500);
  int s4 = gb - s1 - s3;

  // --- CSR build (3 dispatches; scan_top folded into consumers) ---
  hist_pack_kernel<<<256 + 176, 256, 0, stream>>>(
      ei, hist, E, tile, NBUCK, W1, root1, Bh1, Bl1, W2, root2, Bh2, Bl2,
      Wd1, Bd1h);
  scan_rows_gemm_kernel<<<NBUCK + s1, 256, 0, stream>>>(
      hist, rowsum, NBUCK, 0, x, Bh1, Bl1, b1, Hb, z1r, N);
  part_scatter_gemm_kernel<<<256 + s3, 256, 0, stream>>>(
      ei, et, hist, rowsum, rec, E, tile, NBUCK, 256, s1,
      x, Bh1, Bl1, b1, Hb, z1r, N);
  bucket_build_gemm_kernel<<<NBUCK + s4, 256, 0, stream>>>(
      rec, rowsum, sd, erec, N, NBUCK, NBUCK, s1 + s3,
      x, Bh1, Bl1, b1, Hb, z1r);

  // --- layer 1 pull (gemm1 completed inside the chain dispatches) ---
  pull64_kernel<<<((size_t)N * 32 + 255) / 256, 256, 0, stream>>>(Hb, erec, sd, z1r, z1b, N);

  // --- layer 2: K=64 -> 32 (bf16 A, no split) ---
  mfma_gemm2_kernel<<<gb, 256, 0, stream>>>(z1b, Bh2, Bl2, b2, Hb, z2r, N);
  pull32_kernel<<<((size_t)N * 16 + 255) / 256, 256, 0, stream>>>(Hb, erec, sd, z2r, z2b, N);

  // --- decoder (MFMA) ---
  decoder_kernel<<<(P + 63) / 64, 256, 0, stream>>>(z2b, pe, Bd1h, bd1, Wd2, bd2, out, P);
}

// Round 12
// 280.164 us; speedup vs baseline: 1.0594x; 1.0249x over previous
//
#include <hip/hip_runtime.h>
#include <hip/hip_bf16.h>

// ---------------------------------------------------------------------------
// RGCN link predictor. Atomic-free CSR build + CSR-pull + bf16 MFMA GEMMs.
//   rgcn_conv(x) = x@root + b + sum_r segsum_dst( H_r[src] ) / max(cnt_r[dst],1)
//   Pulls: channel-exclusive lane groups + 4-way edge-split per node
//   (shfl_xor combine) + chunk-4 batched gather issue. erec packed to 4B
//   (row | cnt<<19); scale via v_rcp. Plain cached loads/stores.
//   CSR build: 2-level bucket sort by dst (256-dst windows), 256 edge tiles
//   (tile rounded to x4 for int4 alignment). R11: chain loops read 4
//   CONSECUTIVE elements per lane via int4 (1 VMEM inst instead of 4) —
//   chain runs ~1 wave/SIMD so VMEM issue count is the latency multiplier.
//   scan_top folded into consumers. Layer-1 GEMM blocks ride along inside
//   the CSR-chain dispatches. 8 dispatches.
// ---------------------------------------------------------------------------

typedef short bf16x8 __attribute__((ext_vector_type(8)));
typedef float f32x4 __attribute__((ext_vector_type(4)));
typedef float f32x2 __attribute__((ext_vector_type(2)));
typedef unsigned u32x4 __attribute__((ext_vector_type(4)));

__device__ __forceinline__ unsigned short f2bf(float f) {
  union { float f; unsigned u; } x; x.f = f;
  unsigned r = x.u + 0x7FFF + ((x.u >> 16) & 1);  // RNE
  return (unsigned short)(r >> 16);
}
__device__ __forceinline__ float bf2f(unsigned short h) {
  union { unsigned u; float f; } x; x.u = ((unsigned)h) << 16;
  return x.f;
}
__device__ __forceinline__ f32x2 bfpair(unsigned u) {
  union { unsigned u; float f; } a, b;
  a.u = u << 16; b.u = u & 0xFFFF0000u;
  f32x2 r; r[0] = a.f; r[1] = b.f; return r;
}
__device__ __forceinline__ unsigned pk2(float a, float b) {
  return (unsigned)f2bf(a) | ((unsigned)f2bf(b) << 16);
}

// pack weights into MFMA B-fragment order, split hi/lo.
template <int K, int TN>
__device__ __forceinline__ void pack_one(
    int e, const float* __restrict__ W, const float* __restrict__ root,
    ushort* __restrict__ Bh, ushort* __restrict__ Bl) {
  int slab = e / (K * TN), r = e % (K * TN);
  int k = r / TN, n = r % TN;
  float v = (slab < 3) ? W[(size_t)slab * K * TN + k * TN + n] : root[(size_t)k * TN + n];
  int kc = k >> 5, quad = (k >> 3) & 3, j = k & 7, nt = n >> 4, nn = n & 15;
  int NTt = TN / 16;
  int didx = slab * K * TN + ((kc * NTt + nt) * 64 + quad * 16 + nn) * 8 + j;
  unsigned short h = f2bf(v);
  Bh[didx] = h;
  Bl[didx] = f2bf(v - bf2f(h));
}

// blocks 0..255: histogram of dst>>8 per tile (int4 contiguous loads).
// blocks 256..431: weight packing (layer1, layer2, decoder Wd1).
__global__ __launch_bounds__(256) void hist_pack_kernel(
    const int* __restrict__ ei, int* __restrict__ hist, int E, int tile, int NBUCK,
    const float* __restrict__ W1, const float* __restrict__ root1,
    ushort* __restrict__ Bh1, ushort* __restrict__ Bl1,
    const float* __restrict__ W2, const float* __restrict__ root2,
    ushort* __restrict__ Bh2, ushort* __restrict__ Bl2,
    const float* __restrict__ Wd1, ushort* __restrict__ Bd1h) {
  int tid = threadIdx.x;
  if (blockIdx.x >= 256) {
    int e = (blockIdx.x - 256) * 256 + tid;
    if (e < 32768) {
      pack_one<128, 64>(e, W1, root1, Bh1, Bl1);
    } else if (e < 32768 + 8192) {
      pack_one<64, 32>(e - 32768, W2, root2, Bh2, Bl2);
    } else if (e < 32768 + 8192 + 4096) {
      int r = e - 32768 - 8192;          // Wd1: K=64, TN=64, single slab
      int k = r >> 6, n = r & 63;
      int kc = k >> 5, quad = (k >> 3) & 3, j = k & 7, nt = n >> 4, nn = n & 15;
      Bd1h[((kc * 4 + nt) * 64 + quad * 16 + nn) * 8 + j] = f2bf(Wd1[k * 64 + n]);
    }
    return;
  }
  __shared__ int lh[512];
  for (int i = tid; i < 512; i += 256) lh[i] = 0;
  __syncthreads();
  int e0 = blockIdx.x * tile, e1 = min(E, e0 + tile);
  int e = e0 + tid * 4;   // tile%4==0 -> 16B-aligned int4 loads
  for (; e + 3 < e1; e += 1024) {
    int4 d4 = *(const int4*)&ei[E + e];
    atomicAdd(&lh[d4.x >> 8], 1); atomicAdd(&lh[d4.y >> 8], 1);
    atomicAdd(&lh[d4.z >> 8], 1); atomicAdd(&lh[d4.w >> 8], 1);
  }
  for (int ee = e; ee < min(e + 4, e1); ee++) atomicAdd(&lh[ei[E + ee] >> 8], 1);
  __syncthreads();
  for (int i = tid; i < NBUCK; i += 256) hist[i * 256 + blockIdx.x] = lh[i];
}

// ---------------------------------------------------------------------------
// Layer-1 split-bf16 MFMA GEMM as a device body so its blocks can ride along
// inside the CSR-chain dispatches. Block = 4 waves x 16 rows = 64 rows.
// H slabs (0-2): Ah*Bh + Al*Bh, bf16 out. z slab (3): + Ah*Bl, fp32 + bias.
// ---------------------------------------------------------------------------
__device__ __forceinline__ void gemm1_body(
    int bid, int4* __restrict__ bsm,
    const float* __restrict__ A, const ushort* __restrict__ Bh,
    const ushort* __restrict__ Bl, const float* __restrict__ bias,
    ushort* __restrict__ Hb, float* __restrict__ z, int n) {
  constexpr int K = 128, TN = 64;
  constexpr int KC = K / 32;       // 4
  constexpr int NTt = TN / 16;     // 4
  constexpr int HALF = K * TN / 8; // 1024 int4 = 16 KB per half
  const int tid = threadIdx.x;
  const int w = tid >> 6, lane = tid & 63;
  const int quad = lane >> 4, nn = lane & 15;
  const int rowBase = bid * 64 + w * 16;

  int row = rowBase + nn;
  if (row >= n) row = n - 1;  // clamp; stores are guarded
  const float* ap = &A[(size_t)row * K + quad * 8];
  bf16x8 ah[KC], al[KC];
#pragma unroll
  for (int kc = 0; kc < KC; kc++) {
    float4 f0 = *(const float4*)(ap + kc * 32);
    float4 f1 = *(const float4*)(ap + kc * 32 + 4);
    float f[8] = {f0.x, f0.y, f0.z, f0.w, f1.x, f1.y, f1.z, f1.w};
#pragma unroll
    for (int j = 0; j < 8; j++) {
      unsigned short h = f2bf(f[j]);
      ah[kc][j] = (short)h;
      al[kc][j] = (short)f2bf(f[j] - bf2f(h));
    }
  }

  const short* bsp = (const short*)bsm;

#pragma unroll 1
  for (int slab = 0; slab < 4; slab++) {
    __syncthreads();
    {
      const int4* gh = (const int4*)(Bh + (size_t)slab * K * TN);
      for (int i = tid; i < HALF; i += 256) bsm[i] = gh[i];
      if (slab == 3) {
        const int4* gl = (const int4*)(Bl + (size_t)slab * K * TN);
        for (int i = tid; i < HALF; i += 256) bsm[HALF + i] = gl[i];
      }
    }
    __syncthreads();

    f32x4 acc[NTt];
#pragma unroll
    for (int j = 0; j < NTt; j++) acc[j] = (f32x4){0.f, 0.f, 0.f, 0.f};

#pragma unroll
    for (int kc = 0; kc < KC; kc++) {
#pragma unroll
      for (int nt = 0; nt < NTt; nt++) {
        bf16x8 b = *(const bf16x8*)&bsp[((kc * NTt + nt) * 64 + lane) * 8];
        acc[nt] = __builtin_amdgcn_mfma_f32_16x16x32_bf16(ah[kc], b, acc[nt], 0, 0, 0);
        acc[nt] = __builtin_amdgcn_mfma_f32_16x16x32_bf16(al[kc], b, acc[nt], 0, 0, 0);
      }
    }
    if (slab == 3) {
#pragma unroll
      for (int kc = 0; kc < KC; kc++) {
#pragma unroll
        for (int nt = 0; nt < NTt; nt++) {
          bf16x8 b = *(const bf16x8*)&bsp[(HALF * 8) + ((kc * NTt + nt) * 64 + lane) * 8];
          acc[nt] = __builtin_amdgcn_mfma_f32_16x16x32_bf16(ah[kc], b, acc[nt], 0, 0, 0);
        }
      }
    }

    int grow0 = rowBase + quad * 4;
#pragma unroll
    for (int nt = 0; nt < NTt; nt++) {
      int col = nt * 16 + nn;
#pragma unroll
      for (int rg = 0; rg < 4; rg++) {
        int grow = grow0 + rg;
        if (grow < n) {
          float v = acc[nt][rg];
          if (slab == 3) z[(size_t)grow * TN + col] = v + bias[col];
          else Hb[((size_t)slab * n + grow) * TN + col] = f2bf(v);
        }
      }
    }
  }
}

// --- fused chain kernels: blockIdx < nChain -> chain work, else gemm1 slice.
// All share a 32 KB LDS buffer (gemm needs 2*HALF int4; chain aliases ints).

// parallel scan of each bucket row (256 entries) -> exclusive, + rowsum
__global__ __launch_bounds__(256, 4) void scan_rows_gemm_kernel(
    int* __restrict__ hist, int* __restrict__ rowsum, int nChain, int gemmBase,
    const float* __restrict__ A, const ushort* __restrict__ Bh,
    const ushort* __restrict__ Bl, const float* __restrict__ bias,
    ushort* __restrict__ Hb, float* __restrict__ z, int n) {
  __shared__ int4 smem[2048];
  if ((int)blockIdx.x >= nChain) {
    gemm1_body(gemmBase + (int)blockIdx.x - nChain, smem, A, Bh, Bl, bias, Hb, z, n);
    return;
  }
  int* sA = (int*)smem;
  int* sB = sA + 256;
  int t = threadIdx.x;
  int* row = hist + blockIdx.x * 256;
  int v = row[t];
  sA[t] = v;
  __syncthreads();
  int* src = sA; int* dst = sB;
  for (int off = 1; off < 256; off <<= 1) {
    int x = src[t];
    if (t >= off) x += src[t - off];
    dst[t] = x;
    __syncthreads();
    int* tmp = src; src = dst; dst = tmp;
  }
  row[t] = src[t] - v;
  if (t == 255) rowsum[blockIdx.x] = src[255];
}

// scatter edges into coarse buckets. int4 contiguous loads (3 VMEM inst per
// 4 edges vs 12) + batched atomic/store pairs. rowbase via local LDS scan.
__global__ __launch_bounds__(256, 4) void part_scatter_gemm_kernel(
    const int* __restrict__ ei, const int* __restrict__ et,
    const int* __restrict__ hist, const int* __restrict__ rowsum,
    unsigned* __restrict__ rec, int E, int tile, int NBUCK,
    int nChain, int gemmBase,
    const float* __restrict__ A, const ushort* __restrict__ Bh,
    const ushort* __restrict__ Bl, const float* __restrict__ bias,
    ushort* __restrict__ Hb, float* __restrict__ z, int n) {
  __shared__ int4 smem[2048];
  if ((int)blockIdx.x >= nChain) {
    gemm1_body(gemmBase + (int)blockIdx.x - nChain, smem, A, Bh, Bl, bias, Hb, z, n);
    return;
  }
  int* sA = (int*)smem;      // 256
  int* sB = sA + 256;        // 256
  int* rb = sB + 256;        // 512 rowbase
  int* ctr = rb + 512;       // 512
  int t = threadIdx.x;
  // local exclusive scan of rowsum (2 elems/thread, NBUCK <= 511)
  int e0 = 2 * t, e1 = 2 * t + 1;
  int v0 = (e0 < NBUCK) ? rowsum[e0] : 0;
  int v1 = (e1 < NBUCK) ? rowsum[e1] : 0;
  int v = v0 + v1;
  sA[t] = v;
  __syncthreads();
  int* src = sA; int* dst = sB;
  for (int off = 1; off < 256; off <<= 1) {
    int x = src[t];
    if (t >= off) x += src[t - off];
    dst[t] = x;
    __syncthreads();
    int* tmp = src; src = dst; dst = tmp;
  }
  int excl = src[t] - v;
  rb[e0] = excl;
  rb[e1] = excl + v0;
  __syncthreads();
  for (int i = t; i < NBUCK; i += 256)
    ctr[i] = hist[i * 256 + blockIdx.x] + rb[i];
  __syncthreads();
  int e0g = blockIdx.x * tile, e1g = min(E, e0g + tile);
  int e = e0g + t * 4;   // tile%4==0 -> aligned int4
  for (; e + 3 < e1g; e += 1024) {
    int4 s4 = *(const int4*)&ei[e];
    int4 d4 = *(const int4*)&ei[E + e];
    int4 t4 = *(const int4*)&et[e];
    int p0 = atomicAdd(&ctr[d4.x >> 8], 1);
    rec[p0] = (unsigned)(s4.x | (t4.x << 20) | ((d4.x & 255) << 22));
    int p1 = atomicAdd(&ctr[d4.y >> 8], 1);
    rec[p1] = (unsigned)(s4.y | (t4.y << 20) | ((d4.y & 255) << 22));
    int p2 = atomicAdd(&ctr[d4.z >> 8], 1);
    rec[p2] = (unsigned)(s4.z | (t4.z << 20) | ((d4.z & 255) << 22));
    int p3 = atomicAdd(&ctr[d4.w >> 8], 1);
    rec[p3] = (unsigned)(s4.w | (t4.w << 20) | ((d4.w & 255) << 22));
  }
  for (int ee = e; ee < min(e + 4, e1g); ee++) {
    int s = ei[ee];
    int d = ei[E + ee];
    int rt = et[ee];
    int p = atomicAdd(&ctr[d >> 8], 1);
    rec[p] = (unsigned)(s | (rt << 20) | ((d & 255) << 22));
  }
}

// one block per 256-dst window: per-(rel,dst) counts, sd, and final dst-grouped
// erec = (row | cnt<<19) 4B packed. rowbase via local rowsum scan. rec scans
// vectorized int4 with <=3-elem scalar head for alignment.
__global__ __launch_bounds__(256, 4) void bucket_build_gemm_kernel(
    const unsigned* __restrict__ rec, const int* __restrict__ rowsum,
    int2* __restrict__ sd, unsigned* __restrict__ erec, int N, int NBUCK,
    int nChain, int gemmBase,
    const float* __restrict__ A, const ushort* __restrict__ Bh,
    const ushort* __restrict__ Bl, const float* __restrict__ bias,
    ushort* __restrict__ Hb, float* __restrict__ z) {
  __shared__ int4 smem[2048];
  if ((int)blockIdx.x >= nChain) {
    gemm1_body(gemmBase + (int)blockIdx.x - nChain, smem, A, Bh, Bl, bias, Hb, z, N);
    return;
  }
  int* c3 = (int*)smem;       // 768
  int* sA = c3 + 768;         // 256
  int* sB = sA + 256;         // 256
  int* cur = sB + 256;        // 256
  int* rb = cur + 256;        // 512 rowbase
  int tid = threadIdx.x;
  // local exclusive scan of rowsum -> rb (rb[NBUCK] = E automatically)
  {
    int e0 = 2 * tid, e1 = 2 * tid + 1;
    int v0 = (e0 < NBUCK) ? rowsum[e0] : 0;
    int v1 = (e1 < NBUCK) ? rowsum[e1] : 0;
    int v = v0 + v1;
    sA[tid] = v;
    __syncthreads();
    int* src = sA; int* dst = sB;
    for (int off = 1; off < 256; off <<= 1) {
      int x = src[tid];
      if (tid >= off) x += src[tid - off];
      dst[tid] = x;
      __syncthreads();
      int* tmp = src; src = dst; dst = tmp;
    }
    int excl = src[tid] - v;
    rb[e0] = excl;
    rb[e1] = excl + v0;
    __syncthreads();
  }
  int dstBase = blockIdx.x << 8;
  int bs = rb[blockIdx.x], be = rb[blockIdx.x + 1];
  for (int i = tid; i < 768; i += 256) c3[i] = 0;
  __syncthreads();
  int bsa = min((bs + 3) & ~3, be);   // aligned start for int4
  // pass 1: counts
  if (tid < bsa - bs) {
    unsigned r = rec[bs + tid];
    atomicAdd(&c3[((r >> 20) & 3) * 256 + (r >> 22)], 1);
  }
  {
    int i = bsa + tid * 4;
    for (; i + 3 < be; i += 1024) {
      u32x4 r4 = *(const u32x4*)&rec[i];
      atomicAdd(&c3[((r4[0] >> 20) & 3) * 256 + (r4[0] >> 22)], 1);
      atomicAdd(&c3[((r4[1] >> 20) & 3) * 256 + (r4[1] >> 22)], 1);
      atomicAdd(&c3[((r4[2] >> 20) & 3) * 256 + (r4[2] >> 22)], 1);
      atomicAdd(&c3[((r4[3] >> 20) & 3) * 256 + (r4[3] >> 22)], 1);
    }
    for (int ee = i; ee < min(i + 4, be); ee++) {
      unsigned r = rec[ee];
      atomicAdd(&c3[((r >> 20) & 3) * 256 + (r >> 22)], 1);
    }
  }
  __syncthreads();
  int dgv = c3[tid] + c3[256 + tid] + c3[512 + tid];
  sA[tid] = dgv;
  __syncthreads();
  int* src = sA; int* dst = sB;
  for (int off = 1; off < 256; off <<= 1) {
    int x = src[tid];
    if (tid >= off) x += src[tid - off];
    dst[tid] = x;
    __syncthreads();
    int* tmp = src; src = dst; dst = tmp;
  }
  int excl = src[tid] - dgv;
  cur[tid] = bs + excl;
  if (dstBase + tid < N) sd[dstBase + tid] = make_int2(bs + excl, dgv);
  __syncthreads();
  // pass 2: scatter erec (order within (rel,dst) group irrelevant)
  if (tid < bsa - bs) {
    unsigned r = rec[bs + tid];
    int dloc = r >> 22, rt = (r >> 20) & 3;
    int p = atomicAdd(&cur[dloc], 1);
    unsigned cnt = (unsigned)c3[rt * 256 + dloc];
    erec[p] = (unsigned)(rt * N + (int)(r & 0xFFFFF)) | (cnt << 19);
  }
  {
    int i = bsa + tid * 4;
    for (; i + 3 < be; i += 1024) {
      u32x4 r4 = *(const u32x4*)&rec[i];
#pragma unroll
      for (int u = 0; u < 4; u++) {
        unsigned r = r4[u];
        int dloc = r >> 22, rt = (r >> 20) & 3;
        int p = atomicAdd(&cur[dloc], 1);
        unsigned cnt = (unsigned)c3[rt * 256 + dloc];
        erec[p] = (unsigned)(rt * N + (int)(r & 0xFFFFF)) | (cnt << 19);
      }
    }
    for (int ee = i; ee < min(i + 4, be); ee++) {
      unsigned r = rec[ee];
      int dloc = r >> 22, rt = (r >> 20) & 3;
      int p = atomicAdd(&cur[dloc], 1);
      unsigned cnt = (unsigned)c3[rt * 256 + dloc];
      erec[p] = (unsigned)(rt * N + (int)(r & 0xFFFFF)) | (cnt << 19);
    }
  }
}

// Layer-2 pure-bf16 MFMA GEMM (A = z1b bf16, no split). K=64, TN=32.
__global__ __launch_bounds__(256, 4) void mfma_gemm2_kernel(
    const ushort* __restrict__ Ab, const ushort* __restrict__ Bh,
    const ushort* __restrict__ Bl, const float* __restrict__ bias,
    ushort* __restrict__ Hb, float* __restrict__ z2r, int n) {
  constexpr int KC = 2, NTt = 2, HALF = 64 * 32 / 8;
  __shared__ int4 bsm[2 * HALF];
  const int tid = threadIdx.x;
  const int w = tid >> 6, lane = tid & 63;
  const int quad = lane >> 4, nn = lane & 15;
  const int rowBase = blockIdx.x * 64 + w * 16;

  int row = rowBase + nn;
  if (row >= n) row = n - 1;
  const ushort* ap = &Ab[(size_t)row * 64 + quad * 8];
  bf16x8 ah[KC];
  ah[0] = *(const bf16x8*)(ap);
  ah[1] = *(const bf16x8*)(ap + 32);

  const short* bsp = (const short*)bsm;

#pragma unroll 1
  for (int slab = 0; slab < 4; slab++) {
    __syncthreads();
    {
      const int4* gh = (const int4*)(Bh + (size_t)slab * 64 * 32);
      for (int i = tid; i < HALF; i += 256) bsm[i] = gh[i];
      if (slab == 3) {
        const int4* gl = (const int4*)(Bl + (size_t)slab * 64 * 32);
        for (int i = tid; i < HALF; i += 256) bsm[HALF + i] = gl[i];
      }
    }
    __syncthreads();

    f32x4 acc[NTt];
#pragma unroll
    for (int j = 0; j < NTt; j++) acc[j] = (f32x4){0.f, 0.f, 0.f, 0.f};

#pragma unroll
    for (int kc = 0; kc < KC; kc++) {
#pragma unroll
      for (int nt = 0; nt < NTt; nt++) {
        bf16x8 b = *(const bf16x8*)&bsp[((kc * NTt + nt) * 64 + lane) * 8];
        acc[nt] = __builtin_amdgcn_mfma_f32_16x16x32_bf16(ah[kc], b, acc[nt], 0, 0, 0);
      }
    }
    if (slab == 3) {
#pragma unroll
      for (int kc = 0; kc < KC; kc++) {
#pragma unroll
        for (int nt = 0; nt < NTt; nt++) {
          bf16x8 b = *(const bf16x8*)&bsp[(HALF * 8) + ((kc * NTt + nt) * 64 + lane) * 8];
          acc[nt] = __builtin_amdgcn_mfma_f32_16x16x32_bf16(ah[kc], b, acc[nt], 0, 0, 0);
        }
      }
    }

    int grow0 = rowBase + quad * 4;
#pragma unroll
    for (int nt = 0; nt < NTt; nt++) {
      int col = nt * 16 + nn;
#pragma unroll
      for (int rg = 0; rg < 4; rg++) {
        int grow = grow0 + rg;
        if (grow < n) {
          float v = acc[nt][rg];
          if (slab == 3) z2r[(size_t)grow * 32 + col] = v + bias[col];
          else Hb[((size_t)slab * n + grow) * 32 + col] = f2bf(v);
        }
      }
    }
  }
}

// ---- pull, C=64: 32 lanes/node = 8 channel-lanes x 4 edge-quarters.
// Chunk-4 batched issue; 4B erec (row|cnt<<19), v_rcp scale; cached loads.
__global__ __launch_bounds__(256) void pull64_kernel(
    const ushort* __restrict__ Hb, const unsigned* __restrict__ erec,
    const int2* __restrict__ sd, const float* __restrict__ z1r,
    ushort* __restrict__ z1b, int N) {
  int t = blockIdx.x * 256 + threadIdx.x;
  int w = t >> 5;  // node
  if (w >= N) return;
  int q = threadIdx.x & 7;         // channel group (8 ch = 16B)
  int k = (threadIdx.x >> 3) & 3;  // edge quarter
  int2 s2 = sd[w];
  int j0 = s2.x + ((s2.y * k) >> 2);
  int j1 = s2.x + ((s2.y * (k + 1)) >> 2);
  f32x2 a0 = {0.f, 0.f}, a1 = a0, a2 = a0, a3 = a0;
  int j = j0;
  for (; j + 4 <= j1; j += 4) {
    unsigned r0 = erec[j], r1 = erec[j + 1], r2 = erec[j + 2], r3 = erec[j + 3];
    u32x4 v0 = *(const u32x4*)&Hb[(size_t)(r0 & 0x7FFFF) * 64 + q * 8];
    u32x4 v1 = *(const u32x4*)&Hb[(size_t)(r1 & 0x7FFFF) * 64 + q * 8];
    u32x4 v2 = *(const u32x4*)&Hb[(size_t)(r2 & 0x7FFFF) * 64 + q * 8];
    u32x4 v3 = *(const u32x4*)&Hb[(size_t)(r3 & 0x7FFFF) * 64 + q * 8];
    float f0 = __builtin_amdgcn_rcpf((float)(r0 >> 19));
    float f1 = __builtin_amdgcn_rcpf((float)(r1 >> 19));
    float f2 = __builtin_amdgcn_rcpf((float)(r2 >> 19));
    float f3 = __builtin_amdgcn_rcpf((float)(r3 >> 19));
    f32x2 s0 = {f0, f0}, s1 = {f1, f1}, s2v = {f2, f2}, s3 = {f3, f3};
    a0 += bfpair(v0[0]) * s0; a1 += bfpair(v0[1]) * s0;
    a2 += bfpair(v0[2]) * s0; a3 += bfpair(v0[3]) * s0;
    a0 += bfpair(v1[0]) * s1; a1 += bfpair(v1[1]) * s1;
    a2 += bfpair(v1[2]) * s1; a3 += bfpair(v1[3]) * s1;
    a0 += bfpair(v2[0]) * s2v; a1 += bfpair(v2[1]) * s2v;
    a2 += bfpair(v2[2]) * s2v; a3 += bfpair(v2[3]) * s2v;
    a0 += bfpair(v3[0]) * s3; a1 += bfpair(v3[1]) * s3;
    a2 += bfpair(v3[2]) * s3; a3 += bfpair(v3[3]) * s3;
  }
  for (; j < j1; j++) {
    unsigned r = erec[j];
    float sc = __builtin_amdgcn_rcpf((float)(r >> 19));
    f32x2 sc2 = {sc, sc};
    u32x4 v = *(const u32x4*)&Hb[(size_t)(r & 0x7FFFF) * 64 + q * 8];
    a0 += bfpair(v[0]) * sc2;
    a1 += bfpair(v[1]) * sc2;
    a2 += bfpair(v[2]) * sc2;
    a3 += bfpair(v[3]) * sc2;
  }
  // combine the 4 quarters (lanes differing in tid bits 3-4)
#pragma unroll
  for (int m = 8; m <= 16; m <<= 1) {
    a0[0] += __shfl_xor(a0[0], m); a0[1] += __shfl_xor(a0[1], m);
    a1[0] += __shfl_xor(a1[0], m); a1[1] += __shfl_xor(a1[1], m);
    a2[0] += __shfl_xor(a2[0], m); a2[1] += __shfl_xor(a2[1], m);
    a3[0] += __shfl_xor(a3[0], m); a3[1] += __shfl_xor(a3[1], m);
  }
  if (k == 0) {
    const float4* zr = (const float4*)&z1r[(size_t)w * 64 + q * 8];
    float4 r0 = zr[0], r1 = zr[1];
    uint4 st;
    st.x = pk2(fmaxf(r0.x + a0[0], 0.f), fmaxf(r0.y + a0[1], 0.f));
    st.y = pk2(fmaxf(r0.z + a1[0], 0.f), fmaxf(r0.w + a1[1], 0.f));
    st.z = pk2(fmaxf(r1.x + a2[0], 0.f), fmaxf(r1.y + a2[1], 0.f));
    st.w = pk2(fmaxf(r1.z + a3[0], 0.f), fmaxf(r1.w + a3[1], 0.f));
    *(uint4*)&z1b[(size_t)w * 64 + q * 8] = st;
  }
}

// ---- pull, C=32: 16 lanes/node = 4 channel-lanes x 4 edge-quarters.
// Chunk-4 batched issue; 4B erec; shfl_xor (4,8). No ReLU.
__global__ __launch_bounds__(256) void pull32_kernel(
    const ushort* __restrict__ Hb, const unsigned* __restrict__ erec,
    const int2* __restrict__ sd, const float* __restrict__ z2r,
    ushort* __restrict__ z2b, int N) {
  int t = blockIdx.x * 256 + threadIdx.x;
  int w = t >> 4;  // node
  if (w >= N) return;
  int q = threadIdx.x & 3;         // channel group
  int k = (threadIdx.x >> 2) & 3;  // edge quarter
  int2 s2 = sd[w];
  int j0 = s2.x + ((s2.y * k) >> 2);
  int j1 = s2.x + ((s2.y * (k + 1)) >> 2);
  f32x2 a0 = {0.f, 0.f}, a1 = a0, a2 = a0, a3 = a0;
  int j = j0;
  for (; j + 4 <= j1; j += 4) {
    unsigned r0 = erec[j], r1 = erec[j + 1], r2 = erec[j + 2], r3 = erec[j + 3];
    u32x4 v0 = *(const u32x4*)&Hb[(size_t)(r0 & 0x7FFFF) * 32 + q * 8];
    u32x4 v1 = *(const u32x4*)&Hb[(size_t)(r1 & 0x7FFFF) * 32 + q * 8];
    u32x4 v2 = *(const u32x4*)&Hb[(size_t)(r2 & 0x7FFFF) * 32 + q * 8];
    u32x4 v3 = *(const u32x4*)&Hb[(size_t)(r3 & 0x7FFFF) * 32 + q * 8];
    float f0 = __builtin_amdgcn_rcpf((float)(r0 >> 19));
    float f1 = __builtin_amdgcn_rcpf((float)(r1 >> 19));
    float f2 = __builtin_amdgcn_rcpf((float)(r2 >> 19));
    float f3 = __builtin_amdgcn_rcpf((float)(r3 >> 19));
    f32x2 s0 = {f0, f0}, s1 = {f1, f1}, s2v = {f2, f2}, s3 = {f3, f3};
    a0 += bfpair(v0[0]) * s0; a1 += bfpair(v0[1]) * s0;
    a2 += bfpair(v0[2]) * s0; a3 += bfpair(v0[3]) * s0;
    a0 += bfpair(v1[0]) * s1; a1 += bfpair(v1[1]) * s1;
    a2 += bfpair(v1[2]) * s1; a3 += bfpair(v1[3]) * s1;
    a0 += bfpair(v2[0]) * s2v; a1 += bfpair(v2[1]) * s2v;
    a2 += bfpair(v2[2]) * s2v; a3 += bfpair(v2[3]) * s2v;
    a0 += bfpair(v3[0]) * s3; a1 += bfpair(v3[1]) * s3;
    a2 += bfpair(v3[2]) * s3; a3 += bfpair(v3[3]) * s3;
  }
  for (; j < j1; j++) {
    unsigned r = erec[j];
    float sc = __builtin_amdgcn_rcpf((float)(r >> 19));
    f32x2 sc2 = {sc, sc};
    u32x4 v = *(const u32x4*)&Hb[(size_t)(r & 0x7FFFF) * 32 + q * 8];
    a0 += bfpair(v[0]) * sc2;
    a1 += bfpair(v[1]) * sc2;
    a2 += bfpair(v[2]) * sc2;
    a3 += bfpair(v[3]) * sc2;
  }
#pragma unroll
  for (int m = 4; m <= 8; m <<= 1) {
    a0[0] += __shfl_xor(a0[0], m); a0[1] += __shfl_xor(a0[1], m);
    a1[0] += __shfl_xor(a1[0], m); a1[1] += __shfl_xor(a1[1], m);
    a2[0] += __shfl_xor(a2[0], m); a2[1] += __shfl_xor(a2[1], m);
    a3[0] += __shfl_xor(a3[0], m); a3[1] += __shfl_xor(a3[1], m);
  }
  if (k == 0) {
    const float4* zr = (const float4*)&z2r[(size_t)w * 32 + q * 8];
    float4 r0 = zr[0], r1 = zr[1];
    uint4 st;
    st.x = pk2(r0.x + a0[0], r0.y + a0[1]);
    st.y = pk2(r0.z + a1[0], r0.w + a1[1]);
    st.z = pk2(r1.x + a2[0], r1.y + a2[1]);
    st.w = pk2(r1.z + a3[0], r1.w + a3[1]);
    *(uint4*)&z2b[(size_t)w * 32 + q * 8] = st;
  }
}

// MFMA decoder: one wave per 16 pred-edges. ef=[z2b[s],z2b[d]] (K=64) @ Wd1
// (bf16 B-frags, LDS) -> relu -> dot w2. A-frag gathered directly from z2b.
__global__ __launch_bounds__(256) void decoder_kernel(
    const ushort* __restrict__ z2b, const int* __restrict__ pe,
    const ushort* __restrict__ Bd1h, const float* __restrict__ bd1,
    const float* __restrict__ Wd2, const float* __restrict__ bd2,
    float* __restrict__ out, int P) {
  __shared__ int4 wsm[512];  // 4096 bf16 = 8 KB
  __shared__ float b1s[64], w2s[64];
  int tid = threadIdx.x;
  {
    const int4* g = (const int4*)Bd1h;
    for (int i = tid; i < 512; i += 256) wsm[i] = g[i];
    if (tid < 64) { b1s[tid] = bd1[tid]; w2s[tid] = Wd2[tid]; }
  }
  __syncthreads();
  const short* bsp = (const short*)wsm;
  int wv = tid >> 6, lane = tid & 63;
  int quad = lane >> 4, nn = lane & 15;
  int p0 = blockIdx.x * 64 + wv * 16;
  int p = min(p0 + nn, P - 1);  // A-row edge index = lane&15
  int s = pe[p], d = pe[P + p];
  bf16x8 a0 = *(const bf16x8*)&z2b[(size_t)s * 32 + quad * 8];  // k 0..31
  bf16x8 a1 = *(const bf16x8*)&z2b[(size_t)d * 32 + quad * 8];  // k 32..63
  f32x4 acc[4];
#pragma unroll
  for (int nt = 0; nt < 4; nt++) acc[nt] = (f32x4){0.f, 0.f, 0.f, 0.f};
#pragma unroll
  for (int nt = 0; nt < 4; nt++) {
    bf16x8 b0 = *(const bf16x8*)&bsp[((0 * 4 + nt) * 64 + lane) * 8];
    acc[nt] = __builtin_amdgcn_mfma_f32_16x16x32_bf16(a0, b0, acc[nt], 0, 0, 0);
    bf16x8 b1 = *(const bf16x8*)&bsp[((1 * 4 + nt) * 64 + lane) * 8];
    acc[nt] = __builtin_amdgcn_mfma_f32_16x16x32_bf16(a1, b1, acc[nt], 0, 0, 0);
  }
  // D: row(edge)=quad*4+rg, col=nt*16+nn. Per-lane partial over its 4 cols,
  // then reduce across the 16 nn-lanes of this quad.
  float part[4];
#pragma unroll
  for (int rg = 0; rg < 4; rg++) {
    float t = 0.f;
#pragma unroll
    for (int nt = 0; nt < 4; nt++) {
      int col = nt * 16 + nn;
      float h = fmaxf(acc[nt][rg] + b1s[col], 0.f);
      t += h * w2s[col];
    }
    part[rg] = t;
  }
#pragma unroll
  for (int m = 1; m <= 8; m <<= 1)
#pragma unroll
    for (int rg = 0; rg < 4; rg++) part[rg] += __shfl_xor(part[rg], m);
  if (nn == 0) {
    float base = bd2[0];
#pragma unroll
    for (int rg = 0; rg < 4; rg++) {
      int po = p0 + quad * 4 + rg;
      if (po < P) out[po] = part[rg] + base;
    }
  }
}

extern "C" void kernel_launch(void* const* d_in, const int* in_sizes, int n_in,
                              void* d_out, int out_size, void* d_ws, size_t ws_size,
                              hipStream_t stream) {
  const float* x     = (const float*)d_in[0];
  const int*   ei    = (const int*)d_in[1];
  const int*   et    = (const int*)d_in[2];
  const int*   pe    = (const int*)d_in[3];
  const float* W1    = (const float*)d_in[4];
  const float* root1 = (const float*)d_in[5];
  const float* b1    = (const float*)d_in[6];
  const float* W2    = (const float*)d_in[7];
  const float* root2 = (const float*)d_in[8];
  const float* b2    = (const float*)d_in[9];
  const float* Wd1   = (const float*)d_in[10];
  const float* bd1   = (const float*)d_in[11];
  const float* Wd2   = (const float*)d_in[12];
  const float* bd2   = (const float*)d_in[13];
  float* out = (float*)d_out;

  const int N = in_sizes[0] / 128;  // 100000
  const int E = in_sizes[2];        // 1600000
  const int P = in_sizes[3] / 2;    // 200000

  const int NBUCK = (N + 255) >> 8;   // 256-dst windows (<=511 for local scan)
  const int tile  = (((E + 255) / 256) + 3) & ~3;  // per-block edges, x4 aligned

  // Workspace layout (float units; N%4==0 so kN offsets stay 16B-aligned):
  //   z1r:0..64N  z1b(bf16):64N..96N  z2r:96N..128N  z2b(bf16):128N..144N
  //   Hb(bf16):144N..240N  Bpack:240N..241N
  //   ints @241N: sd 2N | erec (E u32, slot 2E) | (unused 1024) | rowsum 1024
  //   | hist NBUCK*256 | rec E
  float* ws   = (float*)d_ws;
  float* z1r  = ws;
  ushort* z1b = (ushort*)(ws + (size_t)64 * N);
  float* z2r  = ws + (size_t)96 * N;
  ushort* z2b = (ushort*)(ws + (size_t)128 * N);
  ushort* Hb  = (ushort*)(ws + (size_t)144 * N);
  ushort* Bh1 = (ushort*)(ws + (size_t)240 * N);  // 32768
  ushort* Bl1 = Bh1 + 32768;                      // 32768
  ushort* Bh2 = Bl1 + 32768;                      // 8192
  ushort* Bl2 = Bh2 + 8192;                       // 8192
  ushort* Bd1h = Bl2 + 8192;                      // 4096
  int* ib      = (int*)(ws + (size_t)241 * N);
  int2* sd     = (int2*)ib;                       // N int2
  unsigned* erec = (unsigned*)(ib + 2 * (size_t)N);   // E u32 (slot holds 2E)
  int* rowsum  = ib + 2 * (size_t)N + 2 * (size_t)E + 1024;  // pad 1024
  int* hist    = rowsum + 1024;                   // NBUCK*256
  unsigned* rec = (unsigned*)(hist + (size_t)NBUCK * 256);  // E

  // gemm1 block slices riding on the CSR-chain dispatches (gemm1 depends only
  // on the packing done in dispatch 1; last slice completes before pull64).
  const int gb = (N + 63) / 64;  // 1563 gemm1 blocks total
  int s1 = min(gb, 400);
  int s3 = min(gb - s1, 500);
  int s4 = gb - s1 - s3;

  // --- CSR build (3 dispatches; scan_top folded into consumers) ---
  hist_pack_kernel<<<256 + 176, 256, 0, stream>>>(
      ei, hist, E, tile, NBUCK, W1, root1, Bh1, Bl1, W2, root2, Bh2, Bl2,
      Wd1, Bd1h);
  scan_rows_gemm_kernel<<<NBUCK + s1, 256, 0, stream>>>(
      hist, rowsum, NBUCK, 0, x, Bh1, Bl1, b1, Hb, z1r, N);
  part_scatter_gemm_kernel<<<256 + s3, 256, 0, stream>>>(
      ei, et, hist, rowsum, rec, E, tile, NBUCK, 256, s1,
      x, Bh1, Bl1, b1, Hb, z1r, N);
  bucket_build_gemm_kernel<<<NBUCK + s4, 256, 0, stream>>>(
      rec, rowsum, sd, erec, N, NBUCK, NBUCK, s1 + s3,
      x, Bh1, Bl1, b1, Hb, z1r);

  // --- layer 1 pull (gemm1 completed inside the chain dispatches) ---
  pull64_kernel<<<((size_t)N * 32 + 255) / 256, 256, 0, stream>>>(Hb, erec, sd, z1r, z1b, N);

  // --- layer 2: K=64 -> 32 (bf16 A, no split) ---
  mfma_gemm2_kernel<<<gb, 256, 0, stream>>>(z1b, Bh2, Bl2, b2, Hb, z2r, N);
  pull32_kernel<<<((size_t)N * 16 + 255) / 256, 256, 0, stream>>>(Hb, erec, sd, z2r, z2b, N);

  // --- decoder (MFMA) ---
  decoder_kernel<<<(P + 63) / 64, 256, 0, stream>>>(z2b, pe, Bd1h, bd1, Wd2, bd2, out, P);
}